// Round 1
// baseline (952.134 us; speedup 1.0000x reference)
//
#include <hip/hip_runtime.h>

#define BB 16
#define CC 192
#define TPIX 3136                       // 56*56
#define NNELE ((size_t)BB * TPIX * CC)  // 9,633,792 elements per [B,T,C] buffer

// ---------------------------------------------------------------------------
// Kernel 1: fused input projections  k/v/r[b,t,d] = sum_c x[b,c,t] * W[d,c]
// Tile: 64 t  x 64 d  x full K=192 (chunks of 16), 3 matrices share the x tile.
// grid (T/64=49, C/64=3, B=16), block 256.
// Thread map: dg = tid&15 (d-group, d=d0+dg*4+j), td = tid>>4 (t-group, t=t0+td*4+i)
// ---------------------------------------------------------------------------
__global__ __launch_bounds__(256) void proj_kernel(
    const float* __restrict__ x,
    const float* __restrict__ Wk, const float* __restrict__ Wv,
    const float* __restrict__ Wr,
    float* __restrict__ kout, float* __restrict__ vout, float* __restrict__ rout)
{
    const int t0 = blockIdx.x * 64;
    const int d0 = blockIdx.y * 64;
    const int b  = blockIdx.z;
    __shared__ float xs[16][64];       // [cc][t]
    __shared__ float ws[3][16][68];    // [m][cc][d] (+4 pad vs bank conflicts)
    const int tid = threadIdx.x;
    const int dg = tid & 15;
    const int td = tid >> 4;

    float acc[3][4][4];                // [m][j=d][i=t]
#pragma unroll
    for (int m = 0; m < 3; ++m)
#pragma unroll
        for (int j = 0; j < 4; ++j)
#pragma unroll
            for (int i = 0; i < 4; ++i) acc[m][j][i] = 0.f;

    const float* const Wm[3] = {Wk, Wv, Wr};

    for (int c0 = 0; c0 < CC; c0 += 16) {
        // stage x tile: 16c x 64t
        {
            const int e  = tid * 4;
            const int cc = e >> 6, tl = e & 63;
            const float4 xv = *(const float4*)&x[((size_t)b * CC + (c0 + cc)) * TPIX + t0 + tl];
            *(float4*)&xs[cc][tl] = xv;
        }
        // stage W tiles (transposed to [cc][d]): 3 x 64d x 16c
        {
            const int c4 = tid & 3;
            const int dd = tid >> 2;   // 0..63
#pragma unroll
            for (int q = 0; q < 3; ++q) {
                const float4 wv = *(const float4*)&Wm[q][(size_t)(d0 + dd) * CC + c0 + c4 * 4];
                ws[q][c4 * 4 + 0][dd] = wv.x;
                ws[q][c4 * 4 + 1][dd] = wv.y;
                ws[q][c4 * 4 + 2][dd] = wv.z;
                ws[q][c4 * 4 + 3][dd] = wv.w;
            }
        }
        __syncthreads();
#pragma unroll 4
        for (int cc = 0; cc < 16; ++cc) {
            const float4 a = *(const float4*)&xs[cc][td * 4];
#pragma unroll
            for (int m = 0; m < 3; ++m) {
                const float4 w = *(const float4*)&ws[m][cc][dg * 4];
                acc[m][0][0] += w.x * a.x; acc[m][0][1] += w.x * a.y;
                acc[m][0][2] += w.x * a.z; acc[m][0][3] += w.x * a.w;
                acc[m][1][0] += w.y * a.x; acc[m][1][1] += w.y * a.y;
                acc[m][1][2] += w.y * a.z; acc[m][1][3] += w.y * a.w;
                acc[m][2][0] += w.z * a.x; acc[m][2][1] += w.z * a.y;
                acc[m][2][2] += w.z * a.z; acc[m][2][3] += w.z * a.w;
                acc[m][3][0] += w.w * a.x; acc[m][3][1] += w.w * a.y;
                acc[m][3][2] += w.w * a.z; acc[m][3][3] += w.w * a.w;
            }
        }
        __syncthreads();
    }

    float* const outp[3] = {kout, vout, rout};
#pragma unroll
    for (int m = 0; m < 3; ++m)
#pragma unroll
        for (int i = 0; i < 4; ++i) {
            const int t = t0 + td * 4 + i;
            const size_t addr = ((size_t)b * TPIX + t) * CC + d0 + dg * 4;
            *(float4*)&outp[m][addr] =
                make_float4(acc[m][0][i], acc[m][1][i], acc[m][2][i], acc[m][3][i]);
        }
}

// ---------------------------------------------------------------------------
// Kernel 2: WKV scan, one thread per (b, c, dir). Both directions atomically
// accumulate 0.5*y into ybuf (zeroed beforehand); exactly two commutative
// fp32 adds per element -> deterministic.
// grid (C/64=3, B=16, 2), block 64.
// ---------------------------------------------------------------------------
__global__ __launch_bounds__(64) void wkv_kernel(
    const float* __restrict__ kb, const float* __restrict__ vb,
    const float* __restrict__ wdec, const float* __restrict__ ubias,
    float* __restrict__ y)
{
    const int c = blockIdx.x * 64 + threadIdx.x;
    const int b = blockIdx.y;
    const bool rev = blockIdx.z != 0;
    const float w = -__expf(wdec[c]);
    const float u = ubias[c];
    float p = 0.f, q = 0.f, o = -1e38f;
    const long stepi = rev ? -(long)CC : (long)CC;
    long idx = (long)b * TPIX * CC + c + (rev ? (long)(TPIX - 1) * CC : 0);
    float kt = kb[idx], vt = vb[idx];
    for (int t = 0; t < TPIX; ++t) {
        const long nidx = idx + stepi;
        float kn = 0.f, vn = 0.f;
        if (t + 1 < TPIX) { kn = kb[nidx]; vn = vb[nidx]; }   // prefetch
        const float uk  = u + kt;
        const float no  = fmaxf(o, uk);
        const float A   = __expf(o - no);
        const float Bw  = __expf(uk - no);
        const float num = A * p + Bw * vt;
        const float den = A * q + Bw;
        const float yv  = __fdividef(num, den);
        const float wo  = w + o;
        const float no2 = fmaxf(wo, kt);
        const float A2  = __expf(wo - no2);
        const float B2  = __expf(kt - no2);
        p = A2 * p + B2 * vt;
        q = A2 * q + B2;
        o = no2;
        atomicAdd(&y[idx], 0.5f * yv);
        idx = nidx; kt = kn; vt = vn;
    }
}

// ---------------------------------------------------------------------------
// Kernel 3: h = LN( sigmoid(r) * y_combined ) over C, one row per block.
// grid B*T, block 192 (3 waves).
// ---------------------------------------------------------------------------
__global__ __launch_bounds__(192) void ln_kernel(
    const float* __restrict__ rbuf, const float* __restrict__ ybuf,
    const float* __restrict__ gamma, const float* __restrict__ beta,
    float* __restrict__ h)
{
    const size_t row = blockIdx.x;
    const int c = threadIdx.x;
    const size_t idx = row * CC + c;
    const float rv = rbuf[idx];
    const float xb = ybuf[idx];
    const float hv = xb / (1.f + __expf(-rv));
    float s = hv, s2 = hv * hv;
#pragma unroll
    for (int off = 1; off < 64; off <<= 1) {
        s  += __shfl_xor(s, off);
        s2 += __shfl_xor(s2, off);
    }
    __shared__ float red[2][3];
    const int wv = threadIdx.x >> 6;
    if ((threadIdx.x & 63) == 0) { red[0][wv] = s; red[1][wv] = s2; }
    __syncthreads();
    s  = red[0][0] + red[0][1] + red[0][2];
    s2 = red[1][0] + red[1][1] + red[1][2];
    const float mu   = s * (1.f / CC);
    const float var  = s2 * (1.f / CC) - mu * mu;
    const float rstd = rsqrtf(var + 1e-5f);
    h[idx] = (hv - mu) * rstd * gamma[c] + beta[c];
}

// ---------------------------------------------------------------------------
// Kernel 4: out[b,d,t] = sum_c h[b,t,c] * Wo[d,c]   (output already transposed)
// grid (49, 3, 16), block 256. tg = tid&15 (t), dq = tid>>4 (d).
// ---------------------------------------------------------------------------
__global__ __launch_bounds__(256) void outproj_kernel(
    const float* __restrict__ h, const float* __restrict__ Wo,
    float* __restrict__ out)
{
    const int t0 = blockIdx.x * 64;
    const int d0 = blockIdx.y * 64;
    const int b  = blockIdx.z;
    __shared__ float hs[16][68];
    __shared__ float wos[16][68];
    const int tid = threadIdx.x;
    const int tg = tid & 15;
    const int dq = tid >> 4;

    float acc[4][4];  // [j=d][i=t]
#pragma unroll
    for (int j = 0; j < 4; ++j)
#pragma unroll
        for (int i = 0; i < 4; ++i) acc[j][i] = 0.f;

    for (int c0 = 0; c0 < CC; c0 += 16) {
        {
            const int c4 = tid & 3;
            const int tl = tid >> 2;   // 0..63
            const float4 hv = *(const float4*)&h[((size_t)b * TPIX + t0 + tl) * CC + c0 + c4 * 4];
            hs[c4 * 4 + 0][tl] = hv.x;
            hs[c4 * 4 + 1][tl] = hv.y;
            hs[c4 * 4 + 2][tl] = hv.z;
            hs[c4 * 4 + 3][tl] = hv.w;
            const float4 wv = *(const float4*)&Wo[(size_t)(d0 + tl) * CC + c0 + c4 * 4];
            wos[c4 * 4 + 0][tl] = wv.x;
            wos[c4 * 4 + 1][tl] = wv.y;
            wos[c4 * 4 + 2][tl] = wv.z;
            wos[c4 * 4 + 3][tl] = wv.w;
        }
        __syncthreads();
#pragma unroll 4
        for (int cc = 0; cc < 16; ++cc) {
            const float4 a = *(const float4*)&hs[cc][tg * 4];
            const float4 w = *(const float4*)&wos[cc][dq * 4];
            acc[0][0] += w.x * a.x; acc[0][1] += w.x * a.y;
            acc[0][2] += w.x * a.z; acc[0][3] += w.x * a.w;
            acc[1][0] += w.y * a.x; acc[1][1] += w.y * a.y;
            acc[1][2] += w.y * a.z; acc[1][3] += w.y * a.w;
            acc[2][0] += w.z * a.x; acc[2][1] += w.z * a.y;
            acc[2][2] += w.z * a.z; acc[2][3] += w.z * a.w;
            acc[3][0] += w.w * a.x; acc[3][1] += w.w * a.y;
            acc[3][2] += w.w * a.z; acc[3][3] += w.w * a.w;
        }
        __syncthreads();
    }

#pragma unroll
    for (int j = 0; j < 4; ++j) {
        const size_t addr = ((size_t)b * CC + d0 + dq * 4 + j) * TPIX + t0 + tg * 4;
        *(float4*)&out[addr] = make_float4(acc[j][0], acc[j][1], acc[j][2], acc[j][3]);
    }
}

// ---------------------------------------------------------------------------
extern "C" void kernel_launch(void* const* d_in, const int* in_sizes, int n_in,
                              void* d_out, int out_size, void* d_ws, size_t ws_size,
                              hipStream_t stream)
{
    const float* x    = (const float*)d_in[0];
    const float* Wk   = (const float*)d_in[1];
    const float* Wv   = (const float*)d_in[2];
    const float* Wr   = (const float*)d_in[3];
    const float* Wo   = (const float*)d_in[4];
    const float* ln_g = (const float*)d_in[5];
    const float* ln_b = (const float*)d_in[6];
    const float* wdec = (const float*)d_in[7];
    const float* u    = (const float*)d_in[8];

    float* kbuf = (float*)d_ws;
    float* vbuf = kbuf + NNELE;
    float* rbuf = vbuf + NNELE;
    float* ybuf = (float*)d_out;   // combined scan output staged in d_out
    float* hbuf = kbuf;            // reuse k buffer after scans
    float* out  = (float*)d_out;

    dim3 g1(TPIX / 64, CC / 64, BB);
    proj_kernel<<<g1, 256, 0, stream>>>(x, Wk, Wv, Wr, kbuf, vbuf, rbuf);

    hipMemsetAsync(ybuf, 0, NNELE * sizeof(float), stream);
    dim3 g2(CC / 64, BB, 2);
    wkv_kernel<<<g2, 64, 0, stream>>>(kbuf, vbuf, wdec, u, ybuf);

    ln_kernel<<<BB * TPIX, 192, 0, stream>>>(rbuf, ybuf, ln_g, ln_b, hbuf);

    outproj_kernel<<<g1, 256, 0, stream>>>(hbuf, Wo, out);
}

// Round 2
// 337.021 us; speedup vs baseline: 2.8251x; 2.8251x over previous
//
#include <hip/hip_runtime.h>

#define BB 16
#define CC 192
#define TPIX 3136                       // 56*56
#define NCH 49                          // chunks per sequence
#define CHL 64                          // chunk length (49*64 = 3136)
#define NNELE ((size_t)BB * TPIX * CC)  // 9,633,792 elements per [B,T,C] buffer
#define NSTATE ((size_t)2 * BB * NCH * CC)  // 301,056 chunk states

// ---------------------------------------------------------------------------
// Kernel 1: fused input projections  k/v/r[b,t,d] = sum_c x[b,c,t] * W[d,c]
// ---------------------------------------------------------------------------
__global__ __launch_bounds__(256) void proj_kernel(
    const float* __restrict__ x,
    const float* __restrict__ Wk, const float* __restrict__ Wv,
    const float* __restrict__ Wr,
    float* __restrict__ kout, float* __restrict__ vout, float* __restrict__ rout)
{
    const int t0 = blockIdx.x * 64;
    const int d0 = blockIdx.y * 64;
    const int b  = blockIdx.z;
    __shared__ float xs[16][64];       // [cc][t]
    __shared__ float ws[3][16][68];    // [m][cc][d] (+4 pad vs bank conflicts)
    const int tid = threadIdx.x;
    const int dg = tid & 15;
    const int td = tid >> 4;

    float acc[3][4][4];                // [m][j=d][i=t]
#pragma unroll
    for (int m = 0; m < 3; ++m)
#pragma unroll
        for (int j = 0; j < 4; ++j)
#pragma unroll
            for (int i = 0; i < 4; ++i) acc[m][j][i] = 0.f;

    const float* const Wm[3] = {Wk, Wv, Wr};

    for (int c0 = 0; c0 < CC; c0 += 16) {
        {
            const int e  = tid * 4;
            const int cc = e >> 6, tl = e & 63;
            const float4 xv = *(const float4*)&x[((size_t)b * CC + (c0 + cc)) * TPIX + t0 + tl];
            *(float4*)&xs[cc][tl] = xv;
        }
        {
            const int c4 = tid & 3;
            const int dd = tid >> 2;   // 0..63
#pragma unroll
            for (int q = 0; q < 3; ++q) {
                const float4 wv = *(const float4*)&Wm[q][(size_t)(d0 + dd) * CC + c0 + c4 * 4];
                ws[q][c4 * 4 + 0][dd] = wv.x;
                ws[q][c4 * 4 + 1][dd] = wv.y;
                ws[q][c4 * 4 + 2][dd] = wv.z;
                ws[q][c4 * 4 + 3][dd] = wv.w;
            }
        }
        __syncthreads();
#pragma unroll 4
        for (int cc = 0; cc < 16; ++cc) {
            const float4 a = *(const float4*)&xs[cc][td * 4];
#pragma unroll
            for (int m = 0; m < 3; ++m) {
                const float4 w = *(const float4*)&ws[m][cc][dg * 4];
                acc[m][0][0] += w.x * a.x; acc[m][0][1] += w.x * a.y;
                acc[m][0][2] += w.x * a.z; acc[m][0][3] += w.x * a.w;
                acc[m][1][0] += w.y * a.x; acc[m][1][1] += w.y * a.y;
                acc[m][1][2] += w.y * a.z; acc[m][1][3] += w.y * a.w;
                acc[m][2][0] += w.z * a.x; acc[m][2][1] += w.z * a.y;
                acc[m][2][2] += w.z * a.z; acc[m][2][3] += w.z * a.w;
                acc[m][3][0] += w.w * a.x; acc[m][3][1] += w.w * a.y;
                acc[m][3][2] += w.w * a.z; acc[m][3][3] += w.w * a.w;
            }
        }
        __syncthreads();
    }

    float* const outp[3] = {kout, vout, rout};
#pragma unroll
    for (int m = 0; m < 3; ++m)
#pragma unroll
        for (int i = 0; i < 4; ++i) {
            const int t = t0 + td * 4 + i;
            const size_t addr = ((size_t)b * TPIX + t) * CC + d0 + dg * 4;
            *(float4*)&outp[m][addr] =
                make_float4(acc[m][0][i], acc[m][1][i], acc[m][2][i], acc[m][3][i]);
        }
}

// ---------------------------------------------------------------------------
// WKV chunked scan. State (p,q,o) means (num,den) = (p,q)*e^o.
// Thread mapping for pass 1/3: gid -> c (fastest), ch, b, dir.
// State arrays indexed by gid directly: sidx = ((dir*BB+b)*NCH+ch)*CC + c.
// ---------------------------------------------------------------------------

// Pass 1: chunk-local scan (identity init), store end state.
__global__ __launch_bounds__(256) void wkv_chunk_kernel(
    const float* __restrict__ kb, const float* __restrict__ vb,
    const float* __restrict__ wdec,
    float* __restrict__ sp, float* __restrict__ sq, float* __restrict__ so)
{
    const int gid = blockIdx.x * 256 + threadIdx.x;
    const int c  = gid % CC;
    const int r  = gid / CC;
    const int ch = r % NCH;
    const int r2 = r / NCH;
    const int b  = r2 % BB;
    const int dir = r2 / BB;

    const float w = -__expf(wdec[c]);
    const int tstart = dir ? (TPIX - 1 - ch * CHL) : (ch * CHL);
    const long stride = dir ? -(long)CC : (long)CC;
    long idx = ((long)b * TPIX + tstart) * CC + c;

    float p = 0.f, q = 0.f, o = -1e38f;
#pragma unroll 4
    for (int j = 0; j < CHL; ++j) {
        const float kt = kb[idx], vt = vb[idx];
        const float wo  = w + o;
        const float no2 = fmaxf(wo, kt);
        const float A2  = __expf(wo - no2);
        const float B2  = __expf(kt - no2);
        p = A2 * p + B2 * vt;
        q = A2 * q + B2;
        o = no2;
        idx += stride;
    }
    sp[gid] = p; sq[gid] = q; so[gid] = o;
}

// Pass 2: in-place exclusive prefix over the 49 chunk states per (dir,b,c).
__global__ __launch_bounds__(256) void wkv_prefix_kernel(
    float* __restrict__ sp, float* __restrict__ sq, float* __restrict__ so,
    const float* __restrict__ wdec)
{
    const int tid = blockIdx.x * 256 + threadIdx.x;   // 0 .. 2*BB*CC-1
    if (tid >= 2 * BB * CC) return;
    const int c  = tid % CC;
    const int g  = tid / CC;                           // dir*BB + b
    const float w  = -__expf(wdec[c]);
    const float wL = w * CHL;

    float P = 0.f, Q = 0.f, O = -1e38f;
    size_t idx = (size_t)g * NCH * CC + c;
    for (int ch = 0; ch < NCH; ++ch) {
        const float pl = sp[idx], ql = sq[idx], ol = so[idx];
        sp[idx] = P; sq[idx] = Q; so[idx] = O;         // exclusive prefix
        const float Ow = O + wL;
        const float no = fmaxf(Ow, ol);
        const float A  = __expf(Ow - no);
        const float Bf = __expf(ol - no);
        P = A * P + Bf * pl;
        Q = A * Q + Bf * ql;
        O = no;
        idx += CC;
    }
}

// Pass 3: re-scan chunk from exclusive prefix, emit y (+= 0.5*y per dir).
__global__ __launch_bounds__(256) void wkv_emit_kernel(
    const float* __restrict__ kb, const float* __restrict__ vb,
    const float* __restrict__ wdec, const float* __restrict__ ubias,
    const float* __restrict__ sp, const float* __restrict__ sq,
    const float* __restrict__ so,
    float* __restrict__ y)
{
    const int gid = blockIdx.x * 256 + threadIdx.x;
    const int c  = gid % CC;
    const int r  = gid / CC;
    const int ch = r % NCH;
    const int r2 = r / NCH;
    const int b  = r2 % BB;
    const int dir = r2 / BB;

    const float w = -__expf(wdec[c]);
    const float u = ubias[c];
    const int tstart = dir ? (TPIX - 1 - ch * CHL) : (ch * CHL);
    const long stride = dir ? -(long)CC : (long)CC;
    long idx = ((long)b * TPIX + tstart) * CC + c;

    float p = sp[gid], q = sq[gid], o = so[gid];
#pragma unroll 2
    for (int j = 0; j < CHL; ++j) {
        const float kt = kb[idx], vt = vb[idx];
        const float uk  = u + kt;
        const float no  = fmaxf(o, uk);
        const float A   = __expf(o - no);
        const float Bw  = __expf(uk - no);
        const float num = A * p + Bw * vt;
        const float den = A * q + Bw;
        const float yv  = __fdividef(num, den);
        atomicAdd(&y[idx], 0.5f * yv);
        const float wo  = w + o;
        const float no2 = fmaxf(wo, kt);
        const float A2  = __expf(wo - no2);
        const float B2  = __expf(kt - no2);
        p = A2 * p + B2 * vt;
        q = A2 * q + B2;
        o = no2;
        idx += stride;
    }
}

// ---------------------------------------------------------------------------
// Kernel 3: h = LN( sigmoid(r) * y_combined ) over C, one row per block.
// ---------------------------------------------------------------------------
__global__ __launch_bounds__(192) void ln_kernel(
    const float* __restrict__ rbuf, const float* __restrict__ ybuf,
    const float* __restrict__ gamma, const float* __restrict__ beta,
    float* __restrict__ h)
{
    const size_t row = blockIdx.x;
    const int c = threadIdx.x;
    const size_t idx = row * CC + c;
    const float rv = rbuf[idx];
    const float xb = ybuf[idx];
    const float hv = xb / (1.f + __expf(-rv));
    float s = hv, s2 = hv * hv;
#pragma unroll
    for (int off = 1; off < 64; off <<= 1) {
        s  += __shfl_xor(s, off);
        s2 += __shfl_xor(s2, off);
    }
    __shared__ float red[2][3];
    const int wv = threadIdx.x >> 6;
    if ((threadIdx.x & 63) == 0) { red[0][wv] = s; red[1][wv] = s2; }
    __syncthreads();
    s  = red[0][0] + red[0][1] + red[0][2];
    s2 = red[1][0] + red[1][1] + red[1][2];
    const float mu   = s * (1.f / CC);
    const float var  = s2 * (1.f / CC) - mu * mu;
    const float rstd = rsqrtf(var + 1e-5f);
    h[idx] = (hv - mu) * rstd * gamma[c] + beta[c];
}

// ---------------------------------------------------------------------------
// Kernel 4: out[b,d,t] = sum_c h[b,t,c] * Wo[d,c]
// ---------------------------------------------------------------------------
__global__ __launch_bounds__(256) void outproj_kernel(
    const float* __restrict__ h, const float* __restrict__ Wo,
    float* __restrict__ out)
{
    const int t0 = blockIdx.x * 64;
    const int d0 = blockIdx.y * 64;
    const int b  = blockIdx.z;
    __shared__ float hs[16][68];
    __shared__ float wos[16][68];
    const int tid = threadIdx.x;
    const int tg = tid & 15;
    const int dq = tid >> 4;

    float acc[4][4];  // [j=d][i=t]
#pragma unroll
    for (int j = 0; j < 4; ++j)
#pragma unroll
        for (int i = 0; i < 4; ++i) acc[j][i] = 0.f;

    for (int c0 = 0; c0 < CC; c0 += 16) {
        {
            const int c4 = tid & 3;
            const int tl = tid >> 2;   // 0..63
            const float4 hv = *(const float4*)&h[((size_t)b * TPIX + t0 + tl) * CC + c0 + c4 * 4];
            hs[c4 * 4 + 0][tl] = hv.x;
            hs[c4 * 4 + 1][tl] = hv.y;
            hs[c4 * 4 + 2][tl] = hv.z;
            hs[c4 * 4 + 3][tl] = hv.w;
            const float4 wv = *(const float4*)&Wo[(size_t)(d0 + tl) * CC + c0 + c4 * 4];
            wos[c4 * 4 + 0][tl] = wv.x;
            wos[c4 * 4 + 1][tl] = wv.y;
            wos[c4 * 4 + 2][tl] = wv.z;
            wos[c4 * 4 + 3][tl] = wv.w;
        }
        __syncthreads();
#pragma unroll 4
        for (int cc = 0; cc < 16; ++cc) {
            const float4 a = *(const float4*)&hs[cc][tg * 4];
            const float4 w = *(const float4*)&wos[cc][dq * 4];
            acc[0][0] += w.x * a.x; acc[0][1] += w.x * a.y;
            acc[0][2] += w.x * a.z; acc[0][3] += w.x * a.w;
            acc[1][0] += w.y * a.x; acc[1][1] += w.y * a.y;
            acc[1][2] += w.y * a.z; acc[1][3] += w.y * a.w;
            acc[2][0] += w.z * a.x; acc[2][1] += w.z * a.y;
            acc[2][2] += w.z * a.z; acc[2][3] += w.z * a.w;
            acc[3][0] += w.w * a.x; acc[3][1] += w.w * a.y;
            acc[3][2] += w.w * a.z; acc[3][3] += w.w * a.w;
        }
        __syncthreads();
    }

#pragma unroll
    for (int j = 0; j < 4; ++j) {
        const size_t addr = ((size_t)b * CC + d0 + dq * 4 + j) * TPIX + t0 + tg * 4;
        *(float4*)&out[addr] = make_float4(acc[j][0], acc[j][1], acc[j][2], acc[j][3]);
    }
}

// ---------------------------------------------------------------------------
extern "C" void kernel_launch(void* const* d_in, const int* in_sizes, int n_in,
                              void* d_out, int out_size, void* d_ws, size_t ws_size,
                              hipStream_t stream)
{
    const float* x    = (const float*)d_in[0];
    const float* Wk   = (const float*)d_in[1];
    const float* Wv   = (const float*)d_in[2];
    const float* Wr   = (const float*)d_in[3];
    const float* Wo   = (const float*)d_in[4];
    const float* ln_g = (const float*)d_in[5];
    const float* ln_b = (const float*)d_in[6];
    const float* wdec = (const float*)d_in[7];
    const float* u    = (const float*)d_in[8];

    float* kbuf = (float*)d_ws;
    float* vbuf = kbuf + NNELE;
    float* rbuf = vbuf + NNELE;
    float* sp   = rbuf + NNELE;
    float* sq   = sp + NSTATE;
    float* so   = sq + NSTATE;
    float* ybuf = (float*)d_out;   // combined scan output staged in d_out
    float* hbuf = kbuf;            // reuse k buffer after scans
    float* out  = (float*)d_out;

    dim3 g1(TPIX / 64, CC / 64, BB);
    proj_kernel<<<g1, 256, 0, stream>>>(x, Wk, Wv, Wr, kbuf, vbuf, rbuf);

    hipMemsetAsync(ybuf, 0, NNELE * sizeof(float), stream);

    const int nth = (int)NSTATE;                  // 301,056
    wkv_chunk_kernel<<<nth / 256, 256, 0, stream>>>(kbuf, vbuf, wdec, sp, sq, so);
    wkv_prefix_kernel<<<(2 * BB * CC + 255) / 256, 256, 0, stream>>>(sp, sq, so, wdec);
    wkv_emit_kernel<<<nth / 256, 256, 0, stream>>>(kbuf, vbuf, wdec, u, sp, sq, so, ybuf);

    ln_kernel<<<BB * TPIX, 192, 0, stream>>>(rbuf, ybuf, ln_g, ln_b, hbuf);

    outproj_kernel<<<g1, 256, 0, stream>>>(hbuf, Wo, out);
}

// Round 3
// 283.867 us; speedup vs baseline: 3.3542x; 1.1872x over previous
//
#include <hip/hip_runtime.h>

#define BB 16
#define CC 192
#define TPIX 3136                       // 56*56
#define NCH 49                          // chunks per sequence
#define CHL 64                          // chunk length (49*64 = 3136)
#define NNELE ((size_t)BB * TPIX * CC)  // 9,633,792 elements per [B,T,C] buffer
#define NSTATE ((size_t)2 * BB * NCH * CC)  // 301,056 chunk states

typedef __attribute__((ext_vector_type(8))) short bf16x8;
typedef __attribute__((ext_vector_type(4))) float f32x4;
typedef __attribute__((ext_vector_type(4))) unsigned short u16x4;

__device__ __forceinline__ unsigned short f2bf(float f) {
    union { float f; unsigned u; } v; v.f = f;
    unsigned r = v.u + 0x7FFFu + ((v.u >> 16) & 1u);   // RNE
    return (unsigned short)(r >> 16);
}
__device__ __forceinline__ float bf2f(unsigned short h) {
    union { unsigned u; float f; } v; v.u = ((unsigned)h) << 16;
    return v.f;
}

// ---------------------------------------------------------------------------
// W convert: 4 matrices [192][192] fp32 -> bf16, concatenated k,v,r,o.
// ---------------------------------------------------------------------------
__global__ __launch_bounds__(256) void wcvt_kernel(
    const float* __restrict__ Wk, const float* __restrict__ Wv,
    const float* __restrict__ Wr, const float* __restrict__ Wo,
    unsigned short* __restrict__ wbf)
{
    const int gid = blockIdx.x * 256 + threadIdx.x;
    const int g = gid * 4;
    const int m = g / (CC * CC);
    const int off = g % (CC * CC);
    const float* W = (m == 0) ? Wk : (m == 1) ? Wv : (m == 2) ? Wr : Wo;
    const float4 w4 = *(const float4*)&W[off];
    u16x4 o;
    o.x = f2bf(w4.x); o.y = f2bf(w4.y); o.z = f2bf(w4.z); o.w = f2bf(w4.w);
    *(u16x4*)&wbf[g] = o;
}

// ---------------------------------------------------------------------------
// x transpose+convert: x[b][c][t] fp32 -> xbf[b][t][c] bf16. 64x64 tiles.
// ---------------------------------------------------------------------------
__global__ __launch_bounds__(256) void xcvt_kernel(
    const float* __restrict__ x, unsigned short* __restrict__ xbf)
{
    const int t0 = blockIdx.x * 64;
    const int c0 = blockIdx.y * 64;
    const int b  = blockIdx.z;
    __shared__ float ls[64][68];
    const int tid = threadIdx.x;
#pragma unroll
    for (int it = 0; it < 4; ++it) {
        const int li = it * 256 + tid;      // 0..1023
        const int ci = li >> 4;
        const int tj = (li & 15) * 4;
        *(float4*)&ls[ci][tj] =
            *(const float4*)&x[((size_t)b * CC + c0 + ci) * TPIX + t0 + tj];
    }
    __syncthreads();
    const int wt = tid >> 2;           // 0..63 (t within tile)
    const int cs = (tid & 3) * 16;     // c segment
    const size_t obase = ((size_t)b * TPIX + t0 + wt) * CC + c0 + cs;
#pragma unroll
    for (int j2 = 0; j2 < 2; ++j2) {
        bf16x8 o;
#pragma unroll
        for (int jj = 0; jj < 8; ++jj)
            o[jj] = (short)f2bf(ls[cs + j2 * 8 + jj][wt]);
        *(bf16x8*)&xbf[obase + j2 * 8] = o;
    }
}

// ---------------------------------------------------------------------------
// Fused projections via MFMA: k/v/r[b,t,d] = sum_c xbf[b,t,c] * W[d,c].
// Pure-register: no LDS, no barriers. Wave = 16 rows x 192 cols x 3 matrices.
// ---------------------------------------------------------------------------
__global__ __launch_bounds__(256) void proj_mfma(
    const unsigned short* __restrict__ xbf,
    const unsigned short* __restrict__ wbf,
    unsigned short* __restrict__ kbf, unsigned short* __restrict__ vbf,
    unsigned short* __restrict__ rbf)
{
    const int lane = threadIdx.x & 63;
    const int wv   = threadIdx.x >> 6;
    const int m0   = blockIdx.x * 64 + wv * 16;   // global row base (b*T + t)
    const int row  = lane & 15;
    const int kg   = lane >> 4;

    bf16x8 af[6];
    const size_t abase = (size_t)(m0 + row) * CC + kg * 8;
#pragma unroll
    for (int kk = 0; kk < 6; ++kk)
        af[kk] = *(const bf16x8*)&xbf[abase + kk * 32];

    unsigned short* const outs[3] = {kbf, vbf, rbf};
#pragma unroll
    for (int m = 0; m < 3; ++m) {
        const unsigned short* wm = wbf + (size_t)m * CC * CC;
        unsigned short* om = outs[m];
#pragma unroll
        for (int n = 0; n < 12; ++n) {
            f32x4 a = {0.f, 0.f, 0.f, 0.f};
            const size_t bbase = (size_t)(n * 16 + row) * CC + kg * 8;
#pragma unroll
            for (int kk = 0; kk < 6; ++kk) {
                const bf16x8 bfr = *(const bf16x8*)&wm[bbase + kk * 32];
                a = __builtin_amdgcn_mfma_f32_16x16x32_bf16(af[kk], bfr, a, 0, 0, 0);
            }
#pragma unroll
            for (int r = 0; r < 4; ++r)
                om[(size_t)(m0 + kg * 4 + r) * CC + n * 16 + row] = f2bf(a[r]);
        }
    }
}

// ---------------------------------------------------------------------------
// Output projection via MFMA: out[b,d,t] = sum_c hbf[b,t,c]*Wo[d,c]
// (fp32 out, transposed store as float4 along t).
// ---------------------------------------------------------------------------
__global__ __launch_bounds__(256) void outproj_mfma(
    const unsigned short* __restrict__ hbf,
    const unsigned short* __restrict__ wo,
    float* __restrict__ out)
{
    const int lane = threadIdx.x & 63;
    const int wv   = threadIdx.x >> 6;
    const int m0   = blockIdx.x * 64 + wv * 16;
    const int row  = lane & 15;
    const int kg   = lane >> 4;
    const int b    = m0 / TPIX;
    const int tb   = m0 % TPIX;

    bf16x8 af[6];
    const size_t abase = (size_t)(m0 + row) * CC + kg * 8;
#pragma unroll
    for (int kk = 0; kk < 6; ++kk)
        af[kk] = *(const bf16x8*)&hbf[abase + kk * 32];

#pragma unroll
    for (int n = 0; n < 12; ++n) {
        f32x4 a = {0.f, 0.f, 0.f, 0.f};
        const size_t bbase = (size_t)(n * 16 + row) * CC + kg * 8;
#pragma unroll
        for (int kk = 0; kk < 6; ++kk) {
            const bf16x8 bfr = *(const bf16x8*)&wo[bbase + kk * 32];
            a = __builtin_amdgcn_mfma_f32_16x16x32_bf16(af[kk], bfr, a, 0, 0, 0);
        }
        const int d = n * 16 + row;
        *(f32x4*)&out[((size_t)b * CC + d) * TPIX + tb + kg * 4] = a;
    }
}

// ---------------------------------------------------------------------------
// WKV chunked scan (bf16 k/v inputs). State (p,q,o): (num,den)=(p,q)*e^o.
// ---------------------------------------------------------------------------
__global__ __launch_bounds__(256) void wkv_chunk_kernel(
    const unsigned short* __restrict__ kb, const unsigned short* __restrict__ vb,
    const float* __restrict__ wdec,
    float* __restrict__ sp, float* __restrict__ sq, float* __restrict__ so)
{
    const int gid = blockIdx.x * 256 + threadIdx.x;
    const int c  = gid % CC;
    const int r  = gid / CC;
    const int ch = r % NCH;
    const int r2 = r / NCH;
    const int b  = r2 % BB;
    const int dir = r2 / BB;

    const float w = -__expf(wdec[c]);
    const int tstart = dir ? (TPIX - 1 - ch * CHL) : (ch * CHL);
    const long stride = dir ? -(long)CC : (long)CC;
    long idx = ((long)b * TPIX + tstart) * CC + c;

    float p = 0.f, q = 0.f, o = -1e38f;
#pragma unroll 4
    for (int j = 0; j < CHL; ++j) {
        const float kt = bf2f(kb[idx]), vt = bf2f(vb[idx]);
        const float wo  = w + o;
        const float no2 = fmaxf(wo, kt);
        const float A2  = __expf(wo - no2);
        const float B2  = __expf(kt - no2);
        p = A2 * p + B2 * vt;
        q = A2 * q + B2;
        o = no2;
        idx += stride;
    }
    sp[gid] = p; sq[gid] = q; so[gid] = o;
}

__global__ __launch_bounds__(256) void wkv_prefix_kernel(
    float* __restrict__ sp, float* __restrict__ sq, float* __restrict__ so,
    const float* __restrict__ wdec)
{
    const int tid = blockIdx.x * 256 + threadIdx.x;
    if (tid >= 2 * BB * CC) return;
    const int c = tid % CC;
    const int g = tid / CC;
    const float w  = -__expf(wdec[c]);
    const float wL = w * CHL;

    float P = 0.f, Q = 0.f, O = -1e38f;
    size_t idx = (size_t)g * NCH * CC + c;
    for (int ch = 0; ch < NCH; ++ch) {
        const float pl = sp[idx], ql = sq[idx], ol = so[idx];
        sp[idx] = P; sq[idx] = Q; so[idx] = O;
        const float Ow = O + wL;
        const float no = fmaxf(Ow, ol);
        const float A  = __expf(Ow - no);
        const float Bf = __expf(ol - no);
        P = A * P + Bf * pl;
        Q = A * Q + Bf * ql;
        O = no;
        idx += CC;
    }
}

__global__ __launch_bounds__(256) void wkv_emit_kernel(
    const unsigned short* __restrict__ kb, const unsigned short* __restrict__ vb,
    const float* __restrict__ wdec, const float* __restrict__ ubias,
    const float* __restrict__ sp, const float* __restrict__ sq,
    const float* __restrict__ so,
    float* __restrict__ y)
{
    const int gid = blockIdx.x * 256 + threadIdx.x;
    const int c  = gid % CC;
    const int r  = gid / CC;
    const int ch = r % NCH;
    const int r2 = r / NCH;
    const int b  = r2 % BB;
    const int dir = r2 / BB;

    const float w = -__expf(wdec[c]);
    const float u = ubias[c];
    const int tstart = dir ? (TPIX - 1 - ch * CHL) : (ch * CHL);
    const long stride = dir ? -(long)CC : (long)CC;
    long idx = ((long)b * TPIX + tstart) * CC + c;

    float p = sp[gid], q = sq[gid], o = so[gid];
#pragma unroll 2
    for (int j = 0; j < CHL; ++j) {
        const float kt = bf2f(kb[idx]), vt = bf2f(vb[idx]);
        const float uk  = u + kt;
        const float no  = fmaxf(o, uk);
        const float A   = __expf(o - no);
        const float Bw  = __expf(uk - no);
        const float num = A * p + Bw * vt;
        const float den = A * q + Bw;
        atomicAdd(&y[idx], 0.5f * __fdividef(num, den));
        const float wo  = w + o;
        const float no2 = fmaxf(wo, kt);
        const float A2  = __expf(wo - no2);
        const float B2  = __expf(kt - no2);
        p = A2 * p + B2 * vt;
        q = A2 * q + B2;
        o = no2;
        idx += stride;
    }
}

// ---------------------------------------------------------------------------
// h = LN( sigmoid(r) * y ) over C; writes bf16 h.
// ---------------------------------------------------------------------------
__global__ __launch_bounds__(192) void ln_kernel(
    const unsigned short* __restrict__ rbf, const float* __restrict__ ybuf,
    const float* __restrict__ gamma, const float* __restrict__ beta,
    unsigned short* __restrict__ hbf)
{
    const size_t row = blockIdx.x;
    const int c = threadIdx.x;
    const size_t idx = row * CC + c;
    const float rv = bf2f(rbf[idx]);
    const float xb = ybuf[idx];
    const float hv = xb / (1.f + __expf(-rv));
    float s = hv, s2 = hv * hv;
#pragma unroll
    for (int off = 1; off < 64; off <<= 1) {
        s  += __shfl_xor(s, off);
        s2 += __shfl_xor(s2, off);
    }
    __shared__ float red[2][3];
    const int wv = threadIdx.x >> 6;
    if ((threadIdx.x & 63) == 0) { red[0][wv] = s; red[1][wv] = s2; }
    __syncthreads();
    s  = red[0][0] + red[0][1] + red[0][2];
    s2 = red[1][0] + red[1][1] + red[1][2];
    const float mu   = s * (1.f / CC);
    const float var  = s2 * (1.f / CC) - mu * mu;
    const float rstd = rsqrtf(var + 1e-5f);
    hbf[idx] = f2bf((hv - mu) * rstd * gamma[c] + beta[c]);
}

// ---------------------------------------------------------------------------
extern "C" void kernel_launch(void* const* d_in, const int* in_sizes, int n_in,
                              void* d_out, int out_size, void* d_ws, size_t ws_size,
                              hipStream_t stream)
{
    const float* x    = (const float*)d_in[0];
    const float* Wk   = (const float*)d_in[1];
    const float* Wv   = (const float*)d_in[2];
    const float* Wr   = (const float*)d_in[3];
    const float* Wo   = (const float*)d_in[4];
    const float* ln_g = (const float*)d_in[5];
    const float* ln_b = (const float*)d_in[6];
    const float* wdec = (const float*)d_in[7];
    const float* u    = (const float*)d_in[8];

    unsigned short* kbf = (unsigned short*)d_ws;
    unsigned short* vbf = kbf + NNELE;
    unsigned short* rbf = vbf + NNELE;
    unsigned short* xbf = rbf + NNELE;
    unsigned short* wbf = xbf + NNELE;          // 4*CC*CC bf16
    float* sp = (float*)xbf;                    // alias: states after proj
    float* sq = sp + NSTATE;
    float* so = sq + NSTATE;
    unsigned short* hbf = kbf;                  // alias: h after scans
    float* ybuf = (float*)d_out;
    float* out  = (float*)d_out;

    wcvt_kernel<<<(4 * CC * CC) / 1024, 256, 0, stream>>>(Wk, Wv, Wr, Wo, wbf);
    xcvt_kernel<<<dim3(TPIX / 64, CC / 64, BB), 256, 0, stream>>>(x, xbf);

    proj_mfma<<<(BB * TPIX) / 64, 256, 0, stream>>>(xbf, wbf, kbf, vbf, rbf);

    hipMemsetAsync(ybuf, 0, NNELE * sizeof(float), stream);
    const int nth = (int)NSTATE;
    wkv_chunk_kernel<<<nth / 256, 256, 0, stream>>>(kbf, vbf, wdec, sp, sq, so);
    wkv_prefix_kernel<<<(2 * BB * CC + 255) / 256, 256, 0, stream>>>(sp, sq, so, wdec);
    wkv_emit_kernel<<<nth / 256, 256, 0, stream>>>(kbf, vbf, wdec, u, sp, sq, so, ybuf);

    ln_kernel<<<BB * TPIX, 192, 0, stream>>>(rbf, ybuf, ln_g, ln_b, hbf);

    outproj_mfma<<<(BB * TPIX) / 64, 256, 0, stream>>>(hbf, wbf + 3 * CC * CC, out);
}

// Round 4
// 223.025 us; speedup vs baseline: 4.2692x; 1.2728x over previous
//
#include <hip/hip_runtime.h>

#define BB 16
#define CC 192
#define TPIX 3136                       // 56*56
#define NCH 49                          // chunks per sequence
#define CHL 64                          // chunk length (49*64 = 3136)
#define NNELE ((size_t)BB * TPIX * CC)  // 9,633,792 elements per [B,T,C] buffer
#define NSTATE ((size_t)2 * BB * NCH * CC)  // 301,056 chunk states

typedef __attribute__((ext_vector_type(8))) short bf16x8;
typedef __attribute__((ext_vector_type(4))) short bf16x4;
typedef __attribute__((ext_vector_type(4))) float f32x4;
typedef __attribute__((ext_vector_type(16))) float f32x16;
typedef __attribute__((ext_vector_type(4))) unsigned short u16x4;

__device__ __forceinline__ unsigned short f2bf(float f) {
    union { float f; unsigned u; } v; v.f = f;
    unsigned r = v.u + 0x7FFFu + ((v.u >> 16) & 1u);   // RNE
    return (unsigned short)(r >> 16);
}
__device__ __forceinline__ float bf2f(unsigned short h) {
    union { unsigned u; float f; } v; v.u = ((unsigned)h) << 16;
    return v.f;
}

// ---------------------------------------------------------------------------
// W convert: 4 matrices [192][192] fp32 -> bf16, concatenated k,v,r,o.
// ---------------------------------------------------------------------------
__global__ __launch_bounds__(256) void wcvt_kernel(
    const float* __restrict__ Wk, const float* __restrict__ Wv,
    const float* __restrict__ Wr, const float* __restrict__ Wo,
    unsigned short* __restrict__ wbf)
{
    const int gid = blockIdx.x * 256 + threadIdx.x;
    const int g = gid * 4;
    const int m = g / (CC * CC);
    const int off = g % (CC * CC);
    const float* W = (m == 0) ? Wk : (m == 1) ? Wv : (m == 2) ? Wr : Wo;
    const float4 w4 = *(const float4*)&W[off];
    u16x4 o;
    o.x = f2bf(w4.x); o.y = f2bf(w4.y); o.z = f2bf(w4.z); o.w = f2bf(w4.w);
    *(u16x4*)&wbf[g] = o;
}

// ---------------------------------------------------------------------------
// x transpose+convert: x[b][c][t] fp32 -> xbf[b][t][c] bf16. 64x64 tiles.
// ---------------------------------------------------------------------------
__global__ __launch_bounds__(256) void xcvt_kernel(
    const float* __restrict__ x, unsigned short* __restrict__ xbf)
{
    const int t0 = blockIdx.x * 64;
    const int c0 = blockIdx.y * 64;
    const int b  = blockIdx.z;
    __shared__ float ls[64][68];
    const int tid = threadIdx.x;
#pragma unroll
    for (int it = 0; it < 4; ++it) {
        const int li = it * 256 + tid;      // 0..1023
        const int ci = li >> 4;
        const int tj = (li & 15) * 4;
        *(float4*)&ls[ci][tj] =
            *(const float4*)&x[((size_t)b * CC + c0 + ci) * TPIX + t0 + tj];
    }
    __syncthreads();
    const int wt = tid >> 2;           // 0..63 (t within tile)
    const int cs = (tid & 3) * 16;     // c segment
    const size_t obase = ((size_t)b * TPIX + t0 + wt) * CC + c0 + cs;
#pragma unroll
    for (int j2 = 0; j2 < 2; ++j2) {
        bf16x8 o;
#pragma unroll
        for (int jj = 0; jj < 8; ++jj)
            o[jj] = (short)f2bf(ls[cs + j2 * 8 + jj][wt]);
        *(bf16x8*)&xbf[obase + j2 * 8] = o;
    }
}

// ---------------------------------------------------------------------------
// Fused projections, 32x32x16 MFMA, register-tiled.
// Block = 4 waves = 128 rows x 192 cols; wave = 64 rows x 96 cols, 3 matrices.
// D = mfma(W_frag, x_frag): lane holds col t = lane&31, rows d contiguous in
// reg quads -> 8B bf16x4 stores to [t][d] layout.
// ---------------------------------------------------------------------------
__global__ __launch_bounds__(256) void proj_mfma32(
    const unsigned short* __restrict__ xbf,
    const unsigned short* __restrict__ wbf,
    unsigned short* __restrict__ kbf, unsigned short* __restrict__ vbf,
    unsigned short* __restrict__ rbf)
{
    const int lane = threadIdx.x & 63;
    const int wv   = threadIdx.x >> 6;
    const int tw   = wv >> 1;              // t-group 0/1
    const int dwav = wv & 1;               // d-group 0/1
    const int rbase = blockIdx.x * 128 + tw * 64;   // global row = b*T + t
    const int l31 = lane & 31;
    const int kh  = lane >> 5;             // 0/1

    unsigned short* const outs[3] = {kbf, vbf, rbf};

#pragma unroll
    for (int m = 0; m < 3; ++m) {
        const unsigned short* wm = wbf + (size_t)m * CC * CC;
        f32x16 acc[2][3];
#pragma unroll
        for (int tt = 0; tt < 2; ++tt)
#pragma unroll
            for (int nn = 0; nn < 3; ++nn)
#pragma unroll
                for (int e = 0; e < 16; ++e) acc[tt][nn][e] = 0.f;

#pragma unroll
        for (int ks = 0; ks < 12; ++ks) {
            bf16x8 xf[2], wf[3];
#pragma unroll
            for (int tt = 0; tt < 2; ++tt)
                xf[tt] = *(const bf16x8*)&xbf[(size_t)(rbase + tt * 32 + l31) * CC + ks * 16 + kh * 8];
#pragma unroll
            for (int nn = 0; nn < 3; ++nn)
                wf[nn] = *(const bf16x8*)&wm[(size_t)(dwav * 96 + nn * 32 + l31) * CC + ks * 16 + kh * 8];
#pragma unroll
            for (int nn = 0; nn < 3; ++nn)
#pragma unroll
                for (int tt = 0; tt < 2; ++tt)
                    acc[tt][nn] = __builtin_amdgcn_mfma_f32_32x32x16_bf16(
                        wf[nn], xf[tt], acc[tt][nn], 0, 0, 0);
        }

        unsigned short* om = outs[m];
#pragma unroll
        for (int tt = 0; tt < 2; ++tt) {
            const size_t trow = (size_t)(rbase + tt * 32 + l31) * CC + dwav * 96 + 4 * kh;
#pragma unroll
            for (int nn = 0; nn < 3; ++nn)
#pragma unroll
                for (int q2 = 0; q2 < 4; ++q2) {
                    bf16x4 pk;
#pragma unroll
                    for (int j = 0; j < 4; ++j)
                        pk[j] = (short)f2bf(acc[tt][nn][q2 * 4 + j]);
                    *(bf16x4*)&om[trow + nn * 32 + 8 * q2] = pk;
                }
        }
    }
}

// ---------------------------------------------------------------------------
// Output projection, 32x32x16 MFMA. D = mfma(h_frag, Wo_frag): lane holds
// col d = lane&31, rows t contiguous in reg quads -> 16B f32x4 stores into
// transposed [b][d][t] output.
// ---------------------------------------------------------------------------
__global__ __launch_bounds__(256) void outproj_mfma32(
    const unsigned short* __restrict__ hbf,
    const unsigned short* __restrict__ wo,
    float* __restrict__ out)
{
    const int lane = threadIdx.x & 63;
    const int wv   = threadIdx.x >> 6;
    const int tw   = wv >> 1;
    const int dwav = wv & 1;
    const int rbase = blockIdx.x * 128 + tw * 64;
    const int l31 = lane & 31;
    const int kh  = lane >> 5;

    f32x16 acc[2][3];
#pragma unroll
    for (int tt = 0; tt < 2; ++tt)
#pragma unroll
        for (int nn = 0; nn < 3; ++nn)
#pragma unroll
            for (int e = 0; e < 16; ++e) acc[tt][nn][e] = 0.f;

#pragma unroll
    for (int ks = 0; ks < 12; ++ks) {
        bf16x8 hf[2], wf[3];
#pragma unroll
        for (int tt = 0; tt < 2; ++tt)
            hf[tt] = *(const bf16x8*)&hbf[(size_t)(rbase + tt * 32 + l31) * CC + ks * 16 + kh * 8];
#pragma unroll
        for (int nn = 0; nn < 3; ++nn)
            wf[nn] = *(const bf16x8*)&wo[(size_t)(dwav * 96 + nn * 32 + l31) * CC + ks * 16 + kh * 8];
#pragma unroll
        for (int nn = 0; nn < 3; ++nn)
#pragma unroll
            for (int tt = 0; tt < 2; ++tt)
                acc[tt][nn] = __builtin_amdgcn_mfma_f32_32x32x16_bf16(
                    hf[tt], wf[nn], acc[tt][nn], 0, 0, 0);
    }

#pragma unroll
    for (int tt = 0; tt < 2; ++tt)
#pragma unroll
        for (int nn = 0; nn < 3; ++nn) {
            const int d = dwav * 96 + nn * 32 + l31;
#pragma unroll
            for (int q2 = 0; q2 < 4; ++q2) {
                const int grow = rbase + tt * 32 + 4 * kh + 8 * q2;  // + j
                const int b  = grow / TPIX;
                const int tl = grow % TPIX;
                f32x4 v4 = {acc[tt][nn][q2 * 4 + 0], acc[tt][nn][q2 * 4 + 1],
                            acc[tt][nn][q2 * 4 + 2], acc[tt][nn][q2 * 4 + 3]};
                *(f32x4*)&out[((size_t)b * CC + d) * TPIX + tl] = v4;
            }
        }
}

// ---------------------------------------------------------------------------
// WKV chunked scan (bf16 k/v inputs). State (p,q,o): (num,den)=(p,q)*e^o.
// ---------------------------------------------------------------------------
__global__ __launch_bounds__(256) void wkv_chunk_kernel(
    const unsigned short* __restrict__ kb, const unsigned short* __restrict__ vb,
    const float* __restrict__ wdec,
    float* __restrict__ sp, float* __restrict__ sq, float* __restrict__ so)
{
    const int gid = blockIdx.x * 256 + threadIdx.x;
    const int c  = gid % CC;
    const int r  = gid / CC;
    const int ch = r % NCH;
    const int r2 = r / NCH;
    const int b  = r2 % BB;
    const int dir = r2 / BB;

    const float w = -__expf(wdec[c]);
    const int tstart = dir ? (TPIX - 1 - ch * CHL) : (ch * CHL);
    const long stride = dir ? -(long)CC : (long)CC;
    long idx = ((long)b * TPIX + tstart) * CC + c;

    float p = 0.f, q = 0.f, o = -1e38f;
#pragma unroll 4
    for (int j = 0; j < CHL; ++j) {
        const float kt = bf2f(kb[idx]), vt = bf2f(vb[idx]);
        const float wo  = w + o;
        const float no2 = fmaxf(wo, kt);
        const float A2  = __expf(wo - no2);
        const float B2  = __expf(kt - no2);
        p = A2 * p + B2 * vt;
        q = A2 * q + B2;
        o = no2;
        idx += stride;
    }
    sp[gid] = p; sq[gid] = q; so[gid] = o;
}

__global__ __launch_bounds__(256) void wkv_prefix_kernel(
    float* __restrict__ sp, float* __restrict__ sq, float* __restrict__ so,
    const float* __restrict__ wdec)
{
    const int tid = blockIdx.x * 256 + threadIdx.x;
    if (tid >= 2 * BB * CC) return;
    const int c = tid % CC;
    const int g = tid / CC;
    const float w  = -__expf(wdec[c]);
    const float wL = w * CHL;

    float P = 0.f, Q = 0.f, O = -1e38f;
    size_t idx = (size_t)g * NCH * CC + c;
    for (int ch = 0; ch < NCH; ++ch) {
        const float pl = sp[idx], ql = sq[idx], ol = so[idx];
        sp[idx] = P; sq[idx] = Q; so[idx] = O;
        const float Ow = O + wL;
        const float no = fmaxf(Ow, ol);
        const float A  = __expf(Ow - no);
        const float Bf = __expf(ol - no);
        P = A * P + Bf * pl;
        Q = A * Q + Bf * ql;
        O = no;
        idx += CC;
    }
}

__global__ __launch_bounds__(256) void wkv_emit_kernel(
    const unsigned short* __restrict__ kb, const unsigned short* __restrict__ vb,
    const float* __restrict__ wdec, const float* __restrict__ ubias,
    const float* __restrict__ sp, const float* __restrict__ sq,
    const float* __restrict__ so,
    float* __restrict__ y)
{
    const int gid = blockIdx.x * 256 + threadIdx.x;
    const int c  = gid % CC;
    const int r  = gid / CC;
    const int ch = r % NCH;
    const int r2 = r / NCH;
    const int b  = r2 % BB;
    const int dir = r2 / BB;

    const float w = -__expf(wdec[c]);
    const float u = ubias[c];
    const int tstart = dir ? (TPIX - 1 - ch * CHL) : (ch * CHL);
    const long stride = dir ? -(long)CC : (long)CC;
    long idx = ((long)b * TPIX + tstart) * CC + c;

    float p = sp[gid], q = sq[gid], o = so[gid];
#pragma unroll 2
    for (int j = 0; j < CHL; ++j) {
        const float kt = bf2f(kb[idx]), vt = bf2f(vb[idx]);
        const float uk  = u + kt;
        const float no  = fmaxf(o, uk);
        const float A   = __expf(o - no);
        const float Bw  = __expf(uk - no);
        const float num = A * p + Bw * vt;
        const float den = A * q + Bw;
        atomicAdd(&y[idx], 0.5f * __fdividef(num, den));
        const float wo  = w + o;
        const float no2 = fmaxf(wo, kt);
        const float A2  = __expf(wo - no2);
        const float B2  = __expf(kt - no2);
        p = A2 * p + B2 * vt;
        q = A2 * q + B2;
        o = no2;
        idx += stride;
    }
}

// ---------------------------------------------------------------------------
// h = LN( sigmoid(r) * y ) over C; writes bf16 h.
// ---------------------------------------------------------------------------
__global__ __launch_bounds__(192) void ln_kernel(
    const unsigned short* __restrict__ rbf, const float* __restrict__ ybuf,
    const float* __restrict__ gamma, const float* __restrict__ beta,
    unsigned short* __restrict__ hbf)
{
    const size_t row = blockIdx.x;
    const int c = threadIdx.x;
    const size_t idx = row * CC + c;
    const float rv = bf2f(rbf[idx]);
    const float xb = ybuf[idx];
    const float hv = xb / (1.f + __expf(-rv));
    float s = hv, s2 = hv * hv;
#pragma unroll
    for (int off = 1; off < 64; off <<= 1) {
        s  += __shfl_xor(s, off);
        s2 += __shfl_xor(s2, off);
    }
    __shared__ float red[2][3];
    const int wv = threadIdx.x >> 6;
    if ((threadIdx.x & 63) == 0) { red[0][wv] = s; red[1][wv] = s2; }
    __syncthreads();
    s  = red[0][0] + red[0][1] + red[0][2];
    s2 = red[1][0] + red[1][1] + red[1][2];
    const float mu   = s * (1.f / CC);
    const float var  = s2 * (1.f / CC) - mu * mu;
    const float rstd = rsqrtf(var + 1e-5f);
    hbf[idx] = f2bf((hv - mu) * rstd * gamma[c] + beta[c]);
}

// ---------------------------------------------------------------------------
extern "C" void kernel_launch(void* const* d_in, const int* in_sizes, int n_in,
                              void* d_out, int out_size, void* d_ws, size_t ws_size,
                              hipStream_t stream)
{
    const float* x    = (const float*)d_in[0];
    const float* Wk   = (const float*)d_in[1];
    const float* Wv   = (const float*)d_in[2];
    const float* Wr   = (const float*)d_in[3];
    const float* Wo   = (const float*)d_in[4];
    const float* ln_g = (const float*)d_in[5];
    const float* ln_b = (const float*)d_in[6];
    const float* wdec = (const float*)d_in[7];
    const float* u    = (const float*)d_in[8];

    unsigned short* kbf = (unsigned short*)d_ws;
    unsigned short* vbf = kbf + NNELE;
    unsigned short* rbf = vbf + NNELE;
    unsigned short* xbf = rbf + NNELE;
    unsigned short* wbf = xbf + NNELE;          // 4*CC*CC bf16
    float* sp = (float*)xbf;                    // alias: states after proj
    float* sq = sp + NSTATE;
    float* so = sq + NSTATE;
    unsigned short* hbf = kbf;                  // alias: h after scans
    float* ybuf = (float*)d_out;
    float* out  = (float*)d_out;

    wcvt_kernel<<<(4 * CC * CC) / 1024, 256, 0, stream>>>(Wk, Wv, Wr, Wo, wbf);
    xcvt_kernel<<<dim3(TPIX / 64, CC / 64, BB), 256, 0, stream>>>(x, xbf);

    proj_mfma32<<<(BB * TPIX) / 128, 256, 0, stream>>>(xbf, wbf, kbf, vbf, rbf);

    hipMemsetAsync(ybuf, 0, NNELE * sizeof(float), stream);
    const int nth = (int)NSTATE;
    wkv_chunk_kernel<<<nth / 256, 256, 0, stream>>>(kbf, vbf, wdec, sp, sq, so);
    wkv_prefix_kernel<<<(2 * BB * CC + 255) / 256, 256, 0, stream>>>(sp, sq, so, wdec);
    wkv_emit_kernel<<<nth / 256, 256, 0, stream>>>(kbf, vbf, wdec, u, sp, sq, so, ybuf);

    ln_kernel<<<BB * TPIX, 192, 0, stream>>>(rbf, ybuf, ln_g, ln_b, hbf);

    outproj_mfma32<<<(BB * TPIX) / 128, 256, 0, stream>>>(hbf, wbf + 3 * CC * CC, out);
}

// Round 5
// 183.215 us; speedup vs baseline: 5.1968x; 1.2173x over previous
//
#include <hip/hip_runtime.h>

#define BB 16
#define CC 192
#define TPIX 3136                       // 56*56
#define NCH 49                          // chunks per sequence
#define CHL 64                          // chunk length (49*64 = 3136)
#define NNELE ((size_t)BB * TPIX * CC)  // 9,633,792 elements per [B,T,C] buffer
#define NSTATE ((size_t)2 * BB * NCH * CC)  // 301,056 chunk states

typedef __attribute__((ext_vector_type(8))) short bf16x8;
typedef __attribute__((ext_vector_type(4))) short bf16x4;
typedef __attribute__((ext_vector_type(4))) float f32x4;
typedef __attribute__((ext_vector_type(16))) float f32x16;
typedef __attribute__((ext_vector_type(4))) unsigned short u16x4;

__device__ __forceinline__ unsigned short f2bf(float f) {
    union { float f; unsigned u; } v; v.f = f;
    unsigned r = v.u + 0x7FFFu + ((v.u >> 16) & 1u);   // RNE
    return (unsigned short)(r >> 16);
}
__device__ __forceinline__ float bf2f(unsigned short h) {
    union { unsigned u; float f; } v; v.u = ((unsigned)h) << 16;
    return v.f;
}

// ---------------------------------------------------------------------------
// W convert: 4 matrices [192][192] fp32 -> bf16, concatenated k,v,r,o.
// ---------------------------------------------------------------------------
__global__ __launch_bounds__(256) void wcvt_kernel(
    const float* __restrict__ Wk, const float* __restrict__ Wv,
    const float* __restrict__ Wr, const float* __restrict__ Wo,
    unsigned short* __restrict__ wbf)
{
    const int gid = blockIdx.x * 256 + threadIdx.x;
    const int g = gid * 4;
    const int m = g / (CC * CC);
    const int off = g % (CC * CC);
    const float* W = (m == 0) ? Wk : (m == 1) ? Wv : (m == 2) ? Wr : Wo;
    const float4 w4 = *(const float4*)&W[off];
    u16x4 o;
    o.x = f2bf(w4.x); o.y = f2bf(w4.y); o.z = f2bf(w4.z); o.w = f2bf(w4.w);
    *(u16x4*)&wbf[g] = o;
}

// ---------------------------------------------------------------------------
// x transpose+convert: x[b][c][t] fp32 -> xbf[b][t][c] bf16. 64x64 tiles.
// ---------------------------------------------------------------------------
__global__ __launch_bounds__(256) void xcvt_kernel(
    const float* __restrict__ x, unsigned short* __restrict__ xbf)
{
    const int t0 = blockIdx.x * 64;
    const int c0 = blockIdx.y * 64;
    const int b  = blockIdx.z;
    __shared__ float ls[64][68];
    const int tid = threadIdx.x;
#pragma unroll
    for (int it = 0; it < 4; ++it) {
        const int li = it * 256 + tid;      // 0..1023
        const int ci = li >> 4;
        const int tj = (li & 15) * 4;
        *(float4*)&ls[ci][tj] =
            *(const float4*)&x[((size_t)b * CC + c0 + ci) * TPIX + t0 + tj];
    }
    __syncthreads();
    const int wt = tid >> 2;           // 0..63 (t within tile)
    const int cs = (tid & 3) * 16;     // c segment
    const size_t obase = ((size_t)b * TPIX + t0 + wt) * CC + c0 + cs;
#pragma unroll
    for (int j2 = 0; j2 < 2; ++j2) {
        bf16x8 o;
#pragma unroll
        for (int jj = 0; jj < 8; ++jj)
            o[jj] = (short)f2bf(ls[cs + j2 * 8 + jj][wt]);
        *(bf16x8*)&xbf[obase + j2 * 8] = o;
    }
}

// ---------------------------------------------------------------------------
// Fused projections, 32x32x16 MFMA, register-tiled, one matrix per blockIdx.z.
// Block = 4 waves = 128 rows x 192 cols; wave = 64 rows x 96 cols.
// D = mfma(W_frag, x_frag): lane holds col t = lane&31, rows d contiguous in
// reg quads -> 8B bf16x4 stores to [t][d] layout.
// ---------------------------------------------------------------------------
__global__ __launch_bounds__(256) void proj_mfma32(
    const unsigned short* __restrict__ xbf,
    const unsigned short* __restrict__ wbf,
    unsigned short* __restrict__ kbf, unsigned short* __restrict__ vbf,
    unsigned short* __restrict__ rbf)
{
    const int lane = threadIdx.x & 63;
    const int wv   = threadIdx.x >> 6;
    const int tw   = wv >> 1;              // t-group 0/1
    const int dwav = wv & 1;               // d-group 0/1
    const int rbase = blockIdx.x * 128 + tw * 64;   // global row = b*T + t
    const int l31 = lane & 31;
    const int kh  = lane >> 5;             // 0/1
    const int m   = blockIdx.z;

    const unsigned short* wm = wbf + (size_t)m * CC * CC;
    f32x16 acc[2][3];
#pragma unroll
    for (int tt = 0; tt < 2; ++tt)
#pragma unroll
        for (int nn = 0; nn < 3; ++nn)
#pragma unroll
            for (int e = 0; e < 16; ++e) acc[tt][nn][e] = 0.f;

#pragma unroll
    for (int ks = 0; ks < 12; ++ks) {
        bf16x8 xf[2], wf[3];
#pragma unroll
        for (int tt = 0; tt < 2; ++tt)
            xf[tt] = *(const bf16x8*)&xbf[(size_t)(rbase + tt * 32 + l31) * CC + ks * 16 + kh * 8];
#pragma unroll
        for (int nn = 0; nn < 3; ++nn)
            wf[nn] = *(const bf16x8*)&wm[(size_t)(dwav * 96 + nn * 32 + l31) * CC + ks * 16 + kh * 8];
#pragma unroll
        for (int nn = 0; nn < 3; ++nn)
#pragma unroll
            for (int tt = 0; tt < 2; ++tt)
                acc[tt][nn] = __builtin_amdgcn_mfma_f32_32x32x16_bf16(
                    wf[nn], xf[tt], acc[tt][nn], 0, 0, 0);
    }

    unsigned short* om = (m == 0) ? kbf : (m == 1) ? vbf : rbf;
#pragma unroll
    for (int tt = 0; tt < 2; ++tt) {
        const size_t trow = (size_t)(rbase + tt * 32 + l31) * CC + dwav * 96 + 4 * kh;
#pragma unroll
        for (int nn = 0; nn < 3; ++nn)
#pragma unroll
            for (int q2 = 0; q2 < 4; ++q2) {
                bf16x4 pk;
#pragma unroll
                for (int j = 0; j < 4; ++j)
                    pk[j] = (short)f2bf(acc[tt][nn][q2 * 4 + j]);
                *(bf16x4*)&om[trow + nn * 32 + 8 * q2] = pk;
            }
    }
}

// ---------------------------------------------------------------------------
// Output projection, 32x32x16 MFMA, wave = 32 rows x 96 d, block 4 waves =
// 64 rows x 192 d, grid 784. D = mfma(h_frag, Wo_frag): lane holds col d,
// rows t contiguous in reg quads -> 16B f32x4 stores into [b][d][t] output.
// ---------------------------------------------------------------------------
__global__ __launch_bounds__(256) void outproj_mfma32(
    const unsigned short* __restrict__ hbf,
    const unsigned short* __restrict__ wo,
    float* __restrict__ out)
{
    const int lane = threadIdx.x & 63;
    const int wv   = threadIdx.x >> 6;
    const int tw   = wv >> 1;              // 0/1 -> 32-row group
    const int dwav = wv & 1;
    const int rbase = blockIdx.x * 64 + tw * 32;
    const int l31 = lane & 31;
    const int kh  = lane >> 5;

    f32x16 acc[3];
#pragma unroll
    for (int nn = 0; nn < 3; ++nn)
#pragma unroll
        for (int e = 0; e < 16; ++e) acc[nn][e] = 0.f;

#pragma unroll
    for (int ks = 0; ks < 12; ++ks) {
        bf16x8 hf, wf[3];
        hf = *(const bf16x8*)&hbf[(size_t)(rbase + l31) * CC + ks * 16 + kh * 8];
#pragma unroll
        for (int nn = 0; nn < 3; ++nn)
            wf[nn] = *(const bf16x8*)&wo[(size_t)(dwav * 96 + nn * 32 + l31) * CC + ks * 16 + kh * 8];
#pragma unroll
        for (int nn = 0; nn < 3; ++nn)
            acc[nn] = __builtin_amdgcn_mfma_f32_32x32x16_bf16(
                hf, wf[nn], acc[nn], 0, 0, 0);
    }

    const int b  = rbase / TPIX;
    const int t0 = rbase % TPIX;
#pragma unroll
    for (int nn = 0; nn < 3; ++nn) {
        const int d = dwav * 96 + nn * 32 + l31;
#pragma unroll
        for (int q2 = 0; q2 < 4; ++q2) {
            const int tl = t0 + 4 * kh + 8 * q2;
            f32x4 v4 = {acc[nn][q2 * 4 + 0], acc[nn][q2 * 4 + 1],
                        acc[nn][q2 * 4 + 2], acc[nn][q2 * 4 + 3]};
            *(f32x4*)&out[((size_t)b * CC + d) * TPIX + tl] = v4;
        }
    }
}

// ---------------------------------------------------------------------------
// WKV chunked scan (bf16 k/v inputs). State (p,q,o): (num,den)=(p,q)*e^o.
// ---------------------------------------------------------------------------
__global__ __launch_bounds__(256) void wkv_chunk_kernel(
    const unsigned short* __restrict__ kb, const unsigned short* __restrict__ vb,
    const float* __restrict__ wdec,
    float* __restrict__ sp, float* __restrict__ sq, float* __restrict__ so)
{
    const int gid = blockIdx.x * 256 + threadIdx.x;
    const int c  = gid % CC;
    const int r  = gid / CC;
    const int ch = r % NCH;
    const int r2 = r / NCH;
    const int b  = r2 % BB;
    const int dir = r2 / BB;

    const float w = -__expf(wdec[c]);
    const int tstart = dir ? (TPIX - 1 - ch * CHL) : (ch * CHL);
    const long stride = dir ? -(long)CC : (long)CC;
    long idx = ((long)b * TPIX + tstart) * CC + c;

    float p = 0.f, q = 0.f, o = -1e38f;
#pragma unroll 4
    for (int j = 0; j < CHL; ++j) {
        const float kt = bf2f(kb[idx]), vt = bf2f(vb[idx]);
        const float wo  = w + o;
        const float no2 = fmaxf(wo, kt);
        const float A2  = __expf(wo - no2);
        const float B2  = __expf(kt - no2);
        p = A2 * p + B2 * vt;
        q = A2 * q + B2;
        o = no2;
        idx += stride;
    }
    sp[gid] = p; sq[gid] = q; so[gid] = o;
}

__global__ __launch_bounds__(256) void wkv_prefix_kernel(
    float* __restrict__ sp, float* __restrict__ sq, float* __restrict__ so,
    const float* __restrict__ wdec)
{
    const int tid = blockIdx.x * 256 + threadIdx.x;
    if (tid >= 2 * BB * CC) return;
    const int c = tid % CC;
    const int g = tid / CC;
    const float w  = -__expf(wdec[c]);
    const float wL = w * CHL;

    float P = 0.f, Q = 0.f, O = -1e38f;
    size_t idx = (size_t)g * NCH * CC + c;
    for (int ch = 0; ch < NCH; ++ch) {
        const float pl = sp[idx], ql = sq[idx], ol = so[idx];
        sp[idx] = P; sq[idx] = Q; so[idx] = O;
        const float Ow = O + wL;
        const float no = fmaxf(Ow, ol);
        const float A  = __expf(Ow - no);
        const float Bf = __expf(ol - no);
        P = A * P + Bf * pl;
        Q = A * Q + Bf * ql;
        O = no;
        idx += CC;
    }
}

// Pass 3: re-scan chunk from exclusive prefix; write bf16(0.5*y) to the
// direction's own buffer (plain stores, each element once -> deterministic).
__global__ __launch_bounds__(256) void wkv_emit_kernel(
    const unsigned short* __restrict__ kb, const unsigned short* __restrict__ vb,
    const float* __restrict__ wdec, const float* __restrict__ ubias,
    const float* __restrict__ sp, const float* __restrict__ sq,
    const float* __restrict__ so,
    unsigned short* __restrict__ yfwd, unsigned short* __restrict__ ybwd)
{
    const int gid = blockIdx.x * 256 + threadIdx.x;
    const int c  = gid % CC;
    const int r  = gid / CC;
    const int ch = r % NCH;
    const int r2 = r / NCH;
    const int b  = r2 % BB;
    const int dir = r2 / BB;

    const float w = -__expf(wdec[c]);
    const float u = ubias[c];
    const int tstart = dir ? (TPIX - 1 - ch * CHL) : (ch * CHL);
    const long stride = dir ? -(long)CC : (long)CC;
    long idx = ((long)b * TPIX + tstart) * CC + c;
    unsigned short* yout = dir ? ybwd : yfwd;

    float p = sp[gid], q = sq[gid], o = so[gid];
#pragma unroll 2
    for (int j = 0; j < CHL; ++j) {
        const float kt = bf2f(kb[idx]), vt = bf2f(vb[idx]);
        const float uk  = u + kt;
        const float no  = fmaxf(o, uk);
        const float A   = __expf(o - no);
        const float Bw  = __expf(uk - no);
        const float num = A * p + Bw * vt;
        const float den = A * q + Bw;
        yout[idx] = f2bf(0.5f * __fdividef(num, den));
        const float wo  = w + o;
        const float no2 = fmaxf(wo, kt);
        const float A2  = __expf(wo - no2);
        const float B2  = __expf(kt - no2);
        p = A2 * p + B2 * vt;
        q = A2 * q + B2;
        o = no2;
        idx += stride;
    }
}

// ---------------------------------------------------------------------------
// h = LN( sigmoid(r) * (yf + yb) ) over C; writes bf16 h.
// ---------------------------------------------------------------------------
__global__ __launch_bounds__(192) void ln_kernel(
    const unsigned short* __restrict__ rbf,
    const unsigned short* __restrict__ yfwd, const unsigned short* __restrict__ ybwd,
    const float* __restrict__ gamma, const float* __restrict__ beta,
    unsigned short* __restrict__ hbf)
{
    const size_t row = blockIdx.x;
    const int c = threadIdx.x;
    const size_t idx = row * CC + c;
    const float rv = bf2f(rbf[idx]);
    const float xb = bf2f(yfwd[idx]) + bf2f(ybwd[idx]);
    const float hv = xb / (1.f + __expf(-rv));
    float s = hv, s2 = hv * hv;
#pragma unroll
    for (int off = 1; off < 64; off <<= 1) {
        s  += __shfl_xor(s, off);
        s2 += __shfl_xor(s2, off);
    }
    __shared__ float red[2][3];
    const int wv = threadIdx.x >> 6;
    if ((threadIdx.x & 63) == 0) { red[0][wv] = s; red[1][wv] = s2; }
    __syncthreads();
    s  = red[0][0] + red[0][1] + red[0][2];
    s2 = red[1][0] + red[1][1] + red[1][2];
    const float mu   = s * (1.f / CC);
    const float var  = s2 * (1.f / CC) - mu * mu;
    const float rstd = rsqrtf(var + 1e-5f);
    hbf[idx] = f2bf((hv - mu) * rstd * gamma[c] + beta[c]);
}

// ---------------------------------------------------------------------------
extern "C" void kernel_launch(void* const* d_in, const int* in_sizes, int n_in,
                              void* d_out, int out_size, void* d_ws, size_t ws_size,
                              hipStream_t stream)
{
    const float* x    = (const float*)d_in[0];
    const float* Wk   = (const float*)d_in[1];
    const float* Wv   = (const float*)d_in[2];
    const float* Wr   = (const float*)d_in[3];
    const float* Wo   = (const float*)d_in[4];
    const float* ln_g = (const float*)d_in[5];
    const float* ln_b = (const float*)d_in[6];
    const float* wdec = (const float*)d_in[7];
    const float* u    = (const float*)d_in[8];

    unsigned short* kbf = (unsigned short*)d_ws;
    unsigned short* vbf = kbf + NNELE;
    unsigned short* rbf = vbf + NNELE;
    unsigned short* xbf = rbf + NNELE;
    unsigned short* wbf = xbf + NNELE;          // 4*CC*CC bf16
    float* sp = (float*)xbf;                    // alias: states after proj
    float* sq = sp + NSTATE;
    float* so = sq + NSTATE;
    unsigned short* hbf = kbf;                  // alias: h after scans
    unsigned short* yfwd = (unsigned short*)d_out;     // bf16 staging in d_out
    unsigned short* ybwd = yfwd + NNELE;
    float* out  = (float*)d_out;

    wcvt_kernel<<<(4 * CC * CC) / 1024, 256, 0, stream>>>(Wk, Wv, Wr, Wo, wbf);
    xcvt_kernel<<<dim3(TPIX / 64, CC / 64, BB), 256, 0, stream>>>(x, xbf);

    proj_mfma32<<<dim3((BB * TPIX) / 128, 1, 3), 256, 0, stream>>>(xbf, wbf, kbf, vbf, rbf);

    const int nth = (int)NSTATE;
    wkv_chunk_kernel<<<nth / 256, 256, 0, stream>>>(kbf, vbf, wdec, sp, sq, so);
    wkv_prefix_kernel<<<(2 * BB * CC + 255) / 256, 256, 0, stream>>>(sp, sq, so, wdec);
    wkv_emit_kernel<<<nth / 256, 256, 0, stream>>>(kbf, vbf, wdec, u, sp, sq, so, yfwd, ybwd);

    ln_kernel<<<BB * TPIX, 192, 0, stream>>>(rbf, yfwd, ybwd, ln_g, ln_b, hbf);

    outproj_mfma32<<<(BB * TPIX) / 64, 256, 0, stream>>>(hbf, wbf + 3 * CC * CC, out);
}

// Round 6
// 151.177 us; speedup vs baseline: 6.2981x; 1.2119x over previous
//
#include <hip/hip_runtime.h>

#define BB 16
#define CC 192
#define TPIX 3136                       // 56*56
#define NCH 49                          // chunks per sequence
#define CHL 64                          // chunk length (49*64 = 3136)
#define NNELE ((size_t)BB * TPIX * CC)  // 9,633,792 elements per [B,T,C] buffer
#define NSTATE ((size_t)2 * BB * NCH * CC)  // 301,056 chunk states
#define WCH (CC * CC)                   // 36864 elems per W matrix

typedef __attribute__((ext_vector_type(8))) short bf16x8;
typedef __attribute__((ext_vector_type(4))) short bf16x4;
typedef __attribute__((ext_vector_type(4))) float f32x4;
typedef __attribute__((ext_vector_type(16))) float f32x16;

__device__ __forceinline__ unsigned short f2bf(float f) {
    union { float f; unsigned u; } v; v.f = f;
    unsigned r = v.u + 0x7FFFu + ((v.u >> 16) & 1u);   // RNE
    return (unsigned short)(r >> 16);
}
__device__ __forceinline__ float bf2f(unsigned short h) {
    union { unsigned u; float f; } v; v.u = ((unsigned)h) << 16;
    return v.f;
}

// Fragment-major layout: for matrix rows x 192 cols, element (row, col) lives at
//   tile = (row>>5)*12 + (col>>4);  lane = (row&31) + ((col>>3)&1)*32;  elem = col&7
//   offset = tile*512 + lane*8 + elem
// A wave's MFMA fragment (32 rows x 16 k) is then one contiguous 1KB block.

// ---------------------------------------------------------------------------
// W convert -> fragment-major bf16, 4 matrices (k,v,r,o).
// 18432 lane-chunks of 16B; grid 72 x 256.
// ---------------------------------------------------------------------------
__global__ __launch_bounds__(256) void wcvt_frag(
    const float* __restrict__ Wk, const float* __restrict__ Wv,
    const float* __restrict__ Wr, const float* __restrict__ Wo,
    unsigned short* __restrict__ wfrag)
{
    const int id = blockIdx.x * 256 + threadIdx.x;    // 0..18431
    const int m = id / 4608;
    const int r = id % 4608;
    const int tile = r >> 6;          // 0..71  (= dr*12 + tk)
    const int lane = r & 63;
    const int dr = tile / 12, tk = tile % 12;
    const int d = dr * 32 + (lane & 31);
    const int c = tk * 16 + (lane >> 5) * 8;
    const float* W = (m == 0) ? Wk : (m == 1) ? Wv : (m == 2) ? Wr : Wo;
    const float4 a = *(const float4*)&W[d * CC + c];
    const float4 b = *(const float4*)&W[d * CC + c + 4];
    bf16x8 o;
    o[0] = (short)f2bf(a.x); o[1] = (short)f2bf(a.y);
    o[2] = (short)f2bf(a.z); o[3] = (short)f2bf(a.w);
    o[4] = (short)f2bf(b.x); o[5] = (short)f2bf(b.y);
    o[6] = (short)f2bf(b.z); o[7] = (short)f2bf(b.w);
    *(bf16x8*)&wfrag[(size_t)m * WCH + (size_t)tile * 512 + lane * 8] = o;
}

// ---------------------------------------------------------------------------
// x transpose+convert -> fragment-major bf16. Block = 32 t x 192 c for one b.
// grid (98, 16) x 256.
// ---------------------------------------------------------------------------
__global__ __launch_bounds__(256) void xcvt_frag(
    const float* __restrict__ x, unsigned short* __restrict__ xfrag)
{
    const int t0 = blockIdx.x * 32;
    const int b  = blockIdx.y;
    __shared__ float ls[CC][33];
    const int tid = threadIdx.x;
#pragma unroll
    for (int it = 0; it < 6; ++it) {
        const int c  = it * 32 + (tid >> 3);
        const int t4 = (tid & 7) * 4;
        *(float4*)&ls[c][t4] =
            *(const float4*)&x[((size_t)b * CC + c) * TPIX + t0 + t4];
    }
    __syncthreads();
    const size_t tbase = ((size_t)(b * TPIX + t0) >> 5) * 12;
#pragma unroll
    for (int it = 0; it < 3; ++it) {
        const int id = it * 256 + tid;          // 0..767
        const int tk = id >> 6;
        const int lane = id & 63;
        const int r32 = lane & 31;
        const int c0 = tk * 16 + (lane >> 5) * 8;
        bf16x8 o;
#pragma unroll
        for (int e = 0; e < 8; ++e)
            o[e] = (short)f2bf(ls[c0 + e][r32]);
        *(bf16x8*)&xfrag[(tbase + tk) * 512 + lane * 8] = o;
    }
}

// ---------------------------------------------------------------------------
// Fused projections, 32x32x16 MFMA, fragment-major operands, no LDS.
// Wave = 32 rows x 96 d; block 4 waves = 64 rows x 192 d; one matrix per z.
// grid (784, 1, 3) x 256.
// ---------------------------------------------------------------------------
__global__ __launch_bounds__(256) void proj_mfma32(
    const unsigned short* __restrict__ xfrag,
    const unsigned short* __restrict__ wfrag,
    unsigned short* __restrict__ kbf, unsigned short* __restrict__ vbf,
    unsigned short* __restrict__ rbf)
{
    const int lane = threadIdx.x & 63;
    const int wv   = threadIdx.x >> 6;
    const int tw   = wv >> 1;
    const int dwav = wv & 1;
    const size_t row0 = (size_t)blockIdx.x * 64 + tw * 32;
    const int l31 = lane & 31;
    const int kh  = lane >> 5;
    const int m   = blockIdx.z;

    const unsigned short* wm = wfrag + (size_t)m * WCH;
    const size_t xtb = (row0 >> 5) * 12;

    f32x16 acc[3];
#pragma unroll
    for (int nn = 0; nn < 3; ++nn)
#pragma unroll
        for (int e = 0; e < 16; ++e) acc[nn][e] = 0.f;

#pragma unroll
    for (int ks = 0; ks < 12; ++ks) {
        const bf16x8 xf = *(const bf16x8*)&xfrag[(xtb + ks) * 512 + lane * 8];
        bf16x8 wf[3];
#pragma unroll
        for (int nn = 0; nn < 3; ++nn)
            wf[nn] = *(const bf16x8*)&wm[(size_t)((dwav * 3 + nn) * 12 + ks) * 512 + lane * 8];
#pragma unroll
        for (int nn = 0; nn < 3; ++nn)
            acc[nn] = __builtin_amdgcn_mfma_f32_32x32x16_bf16(
                wf[nn], xf, acc[nn], 0, 0, 0);
    }

    unsigned short* om = (m == 0) ? kbf : (m == 1) ? vbf : rbf;
    const size_t trow = (row0 + l31) * CC + dwav * 96 + 4 * kh;
#pragma unroll
    for (int nn = 0; nn < 3; ++nn)
#pragma unroll
        for (int q2 = 0; q2 < 4; ++q2) {
            bf16x4 pk;
#pragma unroll
            for (int j = 0; j < 4; ++j)
                pk[j] = (short)f2bf(acc[nn][q2 * 4 + j]);
            *(bf16x4*)&om[trow + nn * 32 + 8 * q2] = pk;
        }
}

// ---------------------------------------------------------------------------
// Output projection, fragment-major h and Wo. Wave = 32 t x 96 d.
// D = mfma(h, Wo): lane col = d, reg quads = consecutive t -> f32x4 stores.
// grid 784 x 256.
// ---------------------------------------------------------------------------
__global__ __launch_bounds__(256) void outproj_mfma32(
    const unsigned short* __restrict__ hfrag,
    const unsigned short* __restrict__ wo,
    float* __restrict__ out)
{
    const int lane = threadIdx.x & 63;
    const int wv   = threadIdx.x >> 6;
    const int tw   = wv >> 1;
    const int dwav = wv & 1;
    const size_t row0 = (size_t)blockIdx.x * 64 + tw * 32;
    const int l31 = lane & 31;
    const int kh  = lane >> 5;

    const size_t htb = (row0 >> 5) * 12;

    f32x16 acc[3];
#pragma unroll
    for (int nn = 0; nn < 3; ++nn)
#pragma unroll
        for (int e = 0; e < 16; ++e) acc[nn][e] = 0.f;

#pragma unroll
    for (int ks = 0; ks < 12; ++ks) {
        const bf16x8 hf = *(const bf16x8*)&hfrag[(htb + ks) * 512 + lane * 8];
        bf16x8 wf[3];
#pragma unroll
        for (int nn = 0; nn < 3; ++nn)
            wf[nn] = *(const bf16x8*)&wo[(size_t)((dwav * 3 + nn) * 12 + ks) * 512 + lane * 8];
#pragma unroll
        for (int nn = 0; nn < 3; ++nn)
            acc[nn] = __builtin_amdgcn_mfma_f32_32x32x16_bf16(
                hf, wf[nn], acc[nn], 0, 0, 0);
    }

    const int b  = (int)(row0 / TPIX);
    const int t0 = (int)(row0 % TPIX);
#pragma unroll
    for (int nn = 0; nn < 3; ++nn) {
        const int d = dwav * 96 + nn * 32 + l31;
#pragma unroll
        for (int q2 = 0; q2 < 4; ++q2) {
            const int tl = t0 + 4 * kh + 8 * q2;
            f32x4 v4 = {acc[nn][q2 * 4 + 0], acc[nn][q2 * 4 + 1],
                        acc[nn][q2 * 4 + 2], acc[nn][q2 * 4 + 3]};
            *(f32x4*)&out[((size_t)b * CC + d) * TPIX + tl] = v4;
        }
    }
}

// ---------------------------------------------------------------------------
// WKV chunked scan (bf16 k/v inputs, [t][c] layout). (num,den)=(p,q)*e^o.
// ---------------------------------------------------------------------------
__global__ __launch_bounds__(256) void wkv_chunk_kernel(
    const unsigned short* __restrict__ kb, const unsigned short* __restrict__ vb,
    const float* __restrict__ wdec,
    float* __restrict__ sp, float* __restrict__ sq, float* __restrict__ so)
{
    const int gid = blockIdx.x * 256 + threadIdx.x;
    const int c  = gid % CC;
    const int r  = gid / CC;
    const int ch = r % NCH;
    const int r2 = r / NCH;
    const int b  = r2 % BB;
    const int dir = r2 / BB;

    const float w = -__expf(wdec[c]);
    const int tstart = dir ? (TPIX - 1 - ch * CHL) : (ch * CHL);
    const long stride = dir ? -(long)CC : (long)CC;
    long idx = ((long)b * TPIX + tstart) * CC + c;

    float p = 0.f, q = 0.f, o = -1e38f;
#pragma unroll 4
    for (int j = 0; j < CHL; ++j) {
        const float kt = bf2f(kb[idx]), vt = bf2f(vb[idx]);
        const float wo  = w + o;
        const float no2 = fmaxf(wo, kt);
        const float A2  = __expf(wo - no2);
        const float B2  = __expf(kt - no2);
        p = A2 * p + B2 * vt;
        q = A2 * q + B2;
        o = no2;
        idx += stride;
    }
    sp[gid] = p; sq[gid] = q; so[gid] = o;
}

__global__ __launch_bounds__(256) void wkv_prefix_kernel(
    float* __restrict__ sp, float* __restrict__ sq, float* __restrict__ so,
    const float* __restrict__ wdec)
{
    const int tid = blockIdx.x * 256 + threadIdx.x;
    if (tid >= 2 * BB * CC) return;
    const int c = tid % CC;
    const int g = tid / CC;
    const float w  = -__expf(wdec[c]);
    const float wL = w * CHL;

    float P = 0.f, Q = 0.f, O = -1e38f;
    size_t idx = (size_t)g * NCH * CC + c;
    for (int ch = 0; ch < NCH; ++ch) {
        const float pl = sp[idx], ql = sq[idx], ol = so[idx];
        sp[idx] = P; sq[idx] = Q; so[idx] = O;
        const float Ow = O + wL;
        const float no = fmaxf(Ow, ol);
        const float A  = __expf(Ow - no);
        const float Bf = __expf(ol - no);
        P = A * P + Bf * pl;
        Q = A * Q + Bf * ql;
        O = no;
        idx += CC;
    }
}

__global__ __launch_bounds__(256) void wkv_emit_kernel(
    const unsigned short* __restrict__ kb, const unsigned short* __restrict__ vb,
    const float* __restrict__ wdec, const float* __restrict__ ubias,
    const float* __restrict__ sp, const float* __restrict__ sq,
    const float* __restrict__ so,
    unsigned short* __restrict__ yfwd, unsigned short* __restrict__ ybwd)
{
    const int gid = blockIdx.x * 256 + threadIdx.x;
    const int c  = gid % CC;
    const int r  = gid / CC;
    const int ch = r % NCH;
    const int r2 = r / NCH;
    const int b  = r2 % BB;
    const int dir = r2 / BB;

    const float w = -__expf(wdec[c]);
    const float u = ubias[c];
    const int tstart = dir ? (TPIX - 1 - ch * CHL) : (ch * CHL);
    const long stride = dir ? -(long)CC : (long)CC;
    long idx = ((long)b * TPIX + tstart) * CC + c;
    unsigned short* yout = dir ? ybwd : yfwd;

    float p = sp[gid], q = sq[gid], o = so[gid];
#pragma unroll 2
    for (int j = 0; j < CHL; ++j) {
        const float kt = bf2f(kb[idx]), vt = bf2f(vb[idx]);
        const float uk  = u + kt;
        const float no  = fmaxf(o, uk);
        const float A   = __expf(o - no);
        const float Bw  = __expf(uk - no);
        const float num = A * p + Bw * vt;
        const float den = A * q + Bw;
        yout[idx] = f2bf(0.5f * __fdividef(num, den));
        const float wo  = w + o;
        const float no2 = fmaxf(wo, kt);
        const float A2  = __expf(wo - no2);
        const float B2  = __expf(kt - no2);
        p = A2 * p + B2 * vt;
        q = A2 * q + B2;
        o = no2;
        idx += stride;
    }
}

// ---------------------------------------------------------------------------
// h = LN( sigmoid(r) * (yf + yb) ) over C; writes h in fragment-major bf16.
// ---------------------------------------------------------------------------
__global__ __launch_bounds__(192) void ln_kernel(
    const unsigned short* __restrict__ rbf,
    const unsigned short* __restrict__ yfwd, const unsigned short* __restrict__ ybwd,
    const float* __restrict__ gamma, const float* __restrict__ beta,
    unsigned short* __restrict__ hfrag)
{
    const size_t row = blockIdx.x;
    const int c = threadIdx.x;
    const size_t idx = row * CC + c;
    const float rv = bf2f(rbf[idx]);
    const float xb = bf2f(yfwd[idx]) + bf2f(ybwd[idx]);
    const float hv = xb / (1.f + __expf(-rv));
    float s = hv, s2 = hv * hv;
#pragma unroll
    for (int off = 1; off < 64; off <<= 1) {
        s  += __shfl_xor(s, off);
        s2 += __shfl_xor(s2, off);
    }
    __shared__ float red[2][3];
    const int wv = threadIdx.x >> 6;
    if ((threadIdx.x & 63) == 0) { red[0][wv] = s; red[1][wv] = s2; }
    __syncthreads();
    s  = red[0][0] + red[0][1] + red[0][2];
    s2 = red[1][0] + red[1][1] + red[1][2];
    const float mu   = s * (1.f / CC);
    const float var  = s2 * (1.f / CC) - mu * mu;
    const float rstd = rsqrtf(var + 1e-5f);
    const float hval = (hv - mu) * rstd * gamma[c] + beta[c];
    const size_t off = ((row >> 5) * 12 + (c >> 4)) * 512 +
                       ((row & 31) + ((c >> 3) & 1) * 32) * 8 + (c & 7);
    hfrag[off] = f2bf(hval);
}

// ---------------------------------------------------------------------------
extern "C" void kernel_launch(void* const* d_in, const int* in_sizes, int n_in,
                              void* d_out, int out_size, void* d_ws, size_t ws_size,
                              hipStream_t stream)
{
    const float* x    = (const float*)d_in[0];
    const float* Wk   = (const float*)d_in[1];
    const float* Wv   = (const float*)d_in[2];
    const float* Wr   = (const float*)d_in[3];
    const float* Wo   = (const float*)d_in[4];
    const float* ln_g = (const float*)d_in[5];
    const float* ln_b = (const float*)d_in[6];
    const float* wdec = (const float*)d_in[7];
    const float* u    = (const float*)d_in[8];

    unsigned short* kbf   = (unsigned short*)d_ws;
    unsigned short* vbf   = kbf + NNELE;
    unsigned short* rbf   = vbf + NNELE;
    unsigned short* xfrag = rbf + NNELE;
    unsigned short* wfrag = xfrag + NNELE;       // 4*WCH bf16
    float* sp = (float*)xfrag;                   // alias: states after proj
    float* sq = sp + NSTATE;
    float* so = sq + NSTATE;
    unsigned short* hfrag = kbf;                 // alias: h after scans
    unsigned short* yfwd  = (unsigned short*)d_out;  // bf16 staging in d_out
    unsigned short* ybwd  = yfwd + NNELE;
    float* out = (float*)d_out;

    wcvt_frag<<<72, 256, 0, stream>>>(Wk, Wv, Wr, Wo, wfrag);
    xcvt_frag<<<dim3(TPIX / 32, BB), 256, 0, stream>>>(x, xfrag);

    proj_mfma32<<<dim3((BB * TPIX) / 64, 1, 3), 256, 0, stream>>>(
        xfrag, wfrag, kbf, vbf, rbf);

    const int nth = (int)NSTATE;
    wkv_chunk_kernel<<<nth / 256, 256, 0, stream>>>(kbf, vbf, wdec, sp, sq, so);
    wkv_prefix_kernel<<<(2 * BB * CC + 255) / 256, 256, 0, stream>>>(sp, sq, so, wdec);
    wkv_emit_kernel<<<nth / 256, 256, 0, stream>>>(kbf, vbf, wdec, u, sp, sq, so, yfwd, ybwd);

    ln_kernel<<<BB * TPIX, 192, 0, stream>>>(rbf, yfwd, ybwd, ln_g, ln_b, hfrag);

    outproj_mfma32<<<(BB * TPIX) / 64, 256, 0, stream>>>(hfrag, wfrag + 3 * WCH, out);
}

// Round 7
// 150.277 us; speedup vs baseline: 6.3359x; 1.0060x over previous
//
#include <hip/hip_runtime.h>

#define BB 16
#define CC 192
#define TPIX 3136                       // 56*56
#define NCH 49                          // chunks per sequence
#define CHL 64                          // chunk length (49*64 = 3136)
#define NNELE ((size_t)BB * TPIX * CC)  // 9,633,792 elements per [B,T,C] buffer
#define NSTATE ((size_t)2 * BB * NCH * CC)  // 301,056 chunk states
#define WCH (CC * CC)                   // 36864 elems per W matrix

typedef __attribute__((ext_vector_type(8))) short bf16x8;
typedef __attribute__((ext_vector_type(4))) short bf16x4;
typedef __attribute__((ext_vector_type(4))) float f32x4;
typedef __attribute__((ext_vector_type(16))) float f32x16;

__device__ __forceinline__ unsigned short f2bf(float f) {
    union { float f; unsigned u; } v; v.f = f;
    unsigned r = v.u + 0x7FFFu + ((v.u >> 16) & 1u);   // RNE
    return (unsigned short)(r >> 16);
}
__device__ __forceinline__ float bf2f(unsigned short h) {
    union { unsigned u; float f; } v; v.u = ((unsigned)h) << 16;
    return v.f;
}

// Fragment-major layout: for matrix rows x 192 cols, element (row, col) lives at
//   tile = (row>>5)*12 + (col>>4);  lane = (row&31) + ((col>>3)&1)*32;  elem = col&7
//   offset = tile*512 + lane*8 + elem
// A wave's MFMA fragment (32 rows x 16 k) is then one contiguous 1KB block.

// ---------------------------------------------------------------------------
// W convert -> fragment-major bf16, 4 matrices (k,v,r,o).
// ---------------------------------------------------------------------------
__global__ __launch_bounds__(256) void wcvt_frag(
    const float* __restrict__ Wk, const float* __restrict__ Wv,
    const float* __restrict__ Wr, const float* __restrict__ Wo,
    unsigned short* __restrict__ wfrag)
{
    const int id = blockIdx.x * 256 + threadIdx.x;    // 0..18431
    const int m = id / 4608;
    const int r = id % 4608;
    const int tile = r >> 6;          // 0..71  (= dr*12 + tk)
    const int lane = r & 63;
    const int dr = tile / 12, tk = tile % 12;
    const int d = dr * 32 + (lane & 31);
    const int c = tk * 16 + (lane >> 5) * 8;
    const float* W = (m == 0) ? Wk : (m == 1) ? Wv : (m == 2) ? Wr : Wo;
    const float4 a = *(const float4*)&W[d * CC + c];
    const float4 b = *(const float4*)&W[d * CC + c + 4];
    bf16x8 o;
    o[0] = (short)f2bf(a.x); o[1] = (short)f2bf(a.y);
    o[2] = (short)f2bf(a.z); o[3] = (short)f2bf(a.w);
    o[4] = (short)f2bf(b.x); o[5] = (short)f2bf(b.y);
    o[6] = (short)f2bf(b.z); o[7] = (short)f2bf(b.w);
    *(bf16x8*)&wfrag[(size_t)m * WCH + (size_t)tile * 512 + lane * 8] = o;
}

// ---------------------------------------------------------------------------
// x transpose+convert -> fragment-major bf16. Block = 32 t x 192 c for one b.
// ---------------------------------------------------------------------------
__global__ __launch_bounds__(256) void xcvt_frag(
    const float* __restrict__ x, unsigned short* __restrict__ xfrag)
{
    const int t0 = blockIdx.x * 32;
    const int b  = blockIdx.y;
    __shared__ float ls[CC][33];
    const int tid = threadIdx.x;
#pragma unroll
    for (int it = 0; it < 6; ++it) {
        const int c  = it * 32 + (tid >> 3);
        const int t4 = (tid & 7) * 4;
        *(float4*)&ls[c][t4] =
            *(const float4*)&x[((size_t)b * CC + c) * TPIX + t0 + t4];
    }
    __syncthreads();
    const size_t tbase = ((size_t)(b * TPIX + t0) >> 5) * 12;
#pragma unroll
    for (int it = 0; it < 3; ++it) {
        const int id = it * 256 + tid;          // 0..767
        const int tk = id >> 6;
        const int lane = id & 63;
        const int r32 = lane & 31;
        const int c0 = tk * 16 + (lane >> 5) * 8;
        bf16x8 o;
#pragma unroll
        for (int e = 0; e < 8; ++e)
            o[e] = (short)f2bf(ls[c0 + e][r32]);
        *(bf16x8*)&xfrag[(tbase + tk) * 512 + lane * 8] = o;
    }
}

// ---------------------------------------------------------------------------
// Fused projections, 32x32x16 MFMA, fragment-major, register double-buffered.
// Wave = 64 t x 96 d (acc 2x3); block 4 waves = 128 t x 192 d; one matrix/z.
// grid (392, 1, 3) x 256.
// ---------------------------------------------------------------------------
__global__ __launch_bounds__(256) void proj_mfma32(
    const unsigned short* __restrict__ xfrag,
    const unsigned short* __restrict__ wfrag,
    unsigned short* __restrict__ kbf, unsigned short* __restrict__ vbf,
    unsigned short* __restrict__ rbf)
{
    const int lane = threadIdx.x & 63;
    const int wv   = threadIdx.x >> 6;
    const int tw   = wv >> 1;              // t-half 0/1
    const int dwav = wv & 1;               // d-half 0/1
    const size_t row0 = (size_t)blockIdx.x * 128 + tw * 64;
    const int l31 = lane & 31;
    const int kh  = lane >> 5;
    const int m   = blockIdx.z;

    const unsigned short* wm = wfrag + (size_t)m * WCH;
    const size_t xtb = (row0 >> 5) * 12;   // x tile base (row0 multiple of 64)

    f32x16 acc[2][3];
#pragma unroll
    for (int tt = 0; tt < 2; ++tt)
#pragma unroll
        for (int nn = 0; nn < 3; ++nn)
#pragma unroll
            for (int e = 0; e < 16; ++e) acc[tt][nn][e] = 0.f;

    bf16x8 xf[2], wf[3];
#pragma unroll
    for (int tt = 0; tt < 2; ++tt)
        xf[tt] = *(const bf16x8*)&xfrag[(xtb + tt * 12) * 512 + lane * 8];
#pragma unroll
    for (int nn = 0; nn < 3; ++nn)
        wf[nn] = *(const bf16x8*)&wm[(size_t)((dwav * 3 + nn) * 12) * 512 + lane * 8];

#pragma unroll
    for (int ks = 0; ks < 12; ++ks) {
        bf16x8 nxf[2], nwf[3];
        if (ks < 11) {
#pragma unroll
            for (int tt = 0; tt < 2; ++tt)
                nxf[tt] = *(const bf16x8*)&xfrag[(xtb + tt * 12 + ks + 1) * 512 + lane * 8];
#pragma unroll
            for (int nn = 0; nn < 3; ++nn)
                nwf[nn] = *(const bf16x8*)&wm[(size_t)((dwav * 3 + nn) * 12 + ks + 1) * 512 + lane * 8];
        }
#pragma unroll
        for (int nn = 0; nn < 3; ++nn)
#pragma unroll
            for (int tt = 0; tt < 2; ++tt)
                acc[tt][nn] = __builtin_amdgcn_mfma_f32_32x32x16_bf16(
                    wf[nn], xf[tt], acc[tt][nn], 0, 0, 0);
        if (ks < 11) {
#pragma unroll
            for (int tt = 0; tt < 2; ++tt) xf[tt] = nxf[tt];
#pragma unroll
            for (int nn = 0; nn < 3; ++nn) wf[nn] = nwf[nn];
        }
    }

    unsigned short* om = (m == 0) ? kbf : (m == 1) ? vbf : rbf;
#pragma unroll
    for (int tt = 0; tt < 2; ++tt) {
        const size_t trow = (row0 + tt * 32 + l31) * CC + dwav * 96 + 4 * kh;
#pragma unroll
        for (int nn = 0; nn < 3; ++nn)
#pragma unroll
            for (int q2 = 0; q2 < 4; ++q2) {
                bf16x4 pk;
#pragma unroll
                for (int j = 0; j < 4; ++j)
                    pk[j] = (short)f2bf(acc[tt][nn][q2 * 4 + j]);
                *(bf16x4*)&om[trow + nn * 32 + 8 * q2] = pk;
            }
    }
}

// ---------------------------------------------------------------------------
// Output projection, fragment-major h and Wo, register double-buffered.
// Wave = 64 t x 96 d; block 4 waves = 128 t x 192 d; grid 392 x 256.
// D = mfma(h, Wo): lane col = d, reg quads = consecutive t -> f32x4 stores.
// ---------------------------------------------------------------------------
__global__ __launch_bounds__(256) void outproj_mfma32(
    const unsigned short* __restrict__ hfrag,
    const unsigned short* __restrict__ wo,
    float* __restrict__ out)
{
    const int lane = threadIdx.x & 63;
    const int wv   = threadIdx.x >> 6;
    const int tw   = wv >> 1;
    const int dwav = wv & 1;
    const size_t row0 = (size_t)blockIdx.x * 128 + tw * 64;
    const int l31 = lane & 31;
    const int kh  = lane >> 5;

    const size_t htb = (row0 >> 5) * 12;

    f32x16 acc[2][3];
#pragma unroll
    for (int tt = 0; tt < 2; ++tt)
#pragma unroll
        for (int nn = 0; nn < 3; ++nn)
#pragma unroll
            for (int e = 0; e < 16; ++e) acc[tt][nn][e] = 0.f;

    bf16x8 hf[2], wf[3];
#pragma unroll
    for (int tt = 0; tt < 2; ++tt)
        hf[tt] = *(const bf16x8*)&hfrag[(htb + tt * 12) * 512 + lane * 8];
#pragma unroll
    for (int nn = 0; nn < 3; ++nn)
        wf[nn] = *(const bf16x8*)&wo[(size_t)((dwav * 3 + nn) * 12) * 512 + lane * 8];

#pragma unroll
    for (int ks = 0; ks < 12; ++ks) {
        bf16x8 nhf[2], nwf[3];
        if (ks < 11) {
#pragma unroll
            for (int tt = 0; tt < 2; ++tt)
                nhf[tt] = *(const bf16x8*)&hfrag[(htb + tt * 12 + ks + 1) * 512 + lane * 8];
#pragma unroll
            for (int nn = 0; nn < 3; ++nn)
                nwf[nn] = *(const bf16x8*)&wo[(size_t)((dwav * 3 + nn) * 12 + ks + 1) * 512 + lane * 8];
        }
#pragma unroll
        for (int nn = 0; nn < 3; ++nn)
#pragma unroll
            for (int tt = 0; tt < 2; ++tt)
                acc[tt][nn] = __builtin_amdgcn_mfma_f32_32x32x16_bf16(
                    hf[tt], wf[nn], acc[tt][nn], 0, 0, 0);
        if (ks < 11) {
#pragma unroll
            for (int tt = 0; tt < 2; ++tt) hf[tt] = nhf[tt];
#pragma unroll
            for (int nn = 0; nn < 3; ++nn) wf[nn] = nwf[nn];
        }
    }

#pragma unroll
    for (int tt = 0; tt < 2; ++tt)
#pragma unroll
        for (int nn = 0; nn < 3; ++nn) {
            const int d = dwav * 96 + nn * 32 + l31;
#pragma unroll
            for (int q2 = 0; q2 < 4; ++q2) {
                const size_t grow = row0 + tt * 32 + 4 * kh + 8 * q2;
                const int b  = (int)(grow / TPIX);
                const int tl = (int)(grow % TPIX);
                f32x4 v4 = {acc[tt][nn][q2 * 4 + 0], acc[tt][nn][q2 * 4 + 1],
                            acc[tt][nn][q2 * 4 + 2], acc[tt][nn][q2 * 4 + 3]};
                *(f32x4*)&out[((size_t)b * CC + d) * TPIX + tl] = v4;
            }
        }
}

// ---------------------------------------------------------------------------
// WKV chunked scan (bf16 k/v inputs, [t][c] layout). (num,den)=(p,q)*e^o.
// ---------------------------------------------------------------------------
__global__ __launch_bounds__(256) void wkv_chunk_kernel(
    const unsigned short* __restrict__ kb, const unsigned short* __restrict__ vb,
    const float* __restrict__ wdec,
    float* __restrict__ sp, float* __restrict__ sq, float* __restrict__ so)
{
    const int gid = blockIdx.x * 256 + threadIdx.x;
    const int c  = gid % CC;
    const int r  = gid / CC;
    const int ch = r % NCH;
    const int r2 = r / NCH;
    const int b  = r2 % BB;
    const int dir = r2 / BB;

    const float w = -__expf(wdec[c]);
    const int tstart = dir ? (TPIX - 1 - ch * CHL) : (ch * CHL);
    const long stride = dir ? -(long)CC : (long)CC;
    long idx = ((long)b * TPIX + tstart) * CC + c;

    float p = 0.f, q = 0.f, o = -1e38f;
#pragma unroll 4
    for (int j = 0; j < CHL; ++j) {
        const float kt = bf2f(kb[idx]), vt = bf2f(vb[idx]);
        const float wo  = w + o;
        const float no2 = fmaxf(wo, kt);
        const float A2  = __expf(wo - no2);
        const float B2  = __expf(kt - no2);
        p = A2 * p + B2 * vt;
        q = A2 * q + B2;
        o = no2;
        idx += stride;
    }
    sp[gid] = p; sq[gid] = q; so[gid] = o;
}

__global__ __launch_bounds__(256) void wkv_prefix_kernel(
    float* __restrict__ sp, float* __restrict__ sq, float* __restrict__ so,
    const float* __restrict__ wdec)
{
    const int tid = blockIdx.x * 256 + threadIdx.x;
    if (tid >= 2 * BB * CC) return;
    const int c = tid % CC;
    const int g = tid / CC;
    const float w  = -__expf(wdec[c]);
    const float wL = w * CHL;

    float P = 0.f, Q = 0.f, O = -1e38f;
    size_t idx = (size_t)g * NCH * CC + c;
    for (int ch = 0; ch < NCH; ++ch) {
        const float pl = sp[idx], ql = sq[idx], ol = so[idx];
        sp[idx] = P; sq[idx] = Q; so[idx] = O;
        const float Ow = O + wL;
        const float no = fmaxf(Ow, ol);
        const float A  = __expf(Ow - no);
        const float Bf = __expf(ol - no);
        P = A * P + Bf * pl;
        Q = A * Q + Bf * ql;
        O = no;
        idx += CC;
    }
}

__global__ __launch_bounds__(256) void wkv_emit_kernel(
    const unsigned short* __restrict__ kb, const unsigned short* __restrict__ vb,
    const float* __restrict__ wdec, const float* __restrict__ ubias,
    const float* __restrict__ sp, const float* __restrict__ sq,
    const float* __restrict__ so,
    unsigned short* __restrict__ yfwd, unsigned short* __restrict__ ybwd)
{
    const int gid = blockIdx.x * 256 + threadIdx.x;
    const int c  = gid % CC;
    const int r  = gid / CC;
    const int ch = r % NCH;
    const int r2 = r / NCH;
    const int b  = r2 % BB;
    const int dir = r2 / BB;

    const float w = -__expf(wdec[c]);
    const float u = ubias[c];
    const int tstart = dir ? (TPIX - 1 - ch * CHL) : (ch * CHL);
    const long stride = dir ? -(long)CC : (long)CC;
    long idx = ((long)b * TPIX + tstart) * CC + c;
    unsigned short* yout = dir ? ybwd : yfwd;

    float p = sp[gid], q = sq[gid], o = so[gid];
#pragma unroll 2
    for (int j = 0; j < CHL; ++j) {
        const float kt = bf2f(kb[idx]), vt = bf2f(vb[idx]);
        const float uk  = u + kt;
        const float no  = fmaxf(o, uk);
        const float A   = __expf(o - no);
        const float Bw  = __expf(uk - no);
        const float num = A * p + Bw * vt;
        const float den = A * q + Bw;
        yout[idx] = f2bf(0.5f * __fdividef(num, den));
        const float wo  = w + o;
        const float no2 = fmaxf(wo, kt);
        const float A2  = __expf(wo - no2);
        const float B2  = __expf(kt - no2);
        p = A2 * p + B2 * vt;
        q = A2 * q + B2;
        o = no2;
        idx += stride;
    }
}

// ---------------------------------------------------------------------------
// h = LN( sigmoid(r) * (yf + yb) ) over C; writes h in fragment-major bf16.
// ---------------------------------------------------------------------------
__global__ __launch_bounds__(192) void ln_kernel(
    const unsigned short* __restrict__ rbf,
    const unsigned short* __restrict__ yfwd, const unsigned short* __restrict__ ybwd,
    const float* __restrict__ gamma, const float* __restrict__ beta,
    unsigned short* __restrict__ hfrag)
{
    const size_t row = blockIdx.x;
    const int c = threadIdx.x;
    const size_t idx = row * CC + c;
    const float rv = bf2f(rbf[idx]);
    const float xb = bf2f(yfwd[idx]) + bf2f(ybwd[idx]);
    const float hv = xb / (1.f + __expf(-rv));
    float s = hv, s2 = hv * hv;
#pragma unroll
    for (int off = 1; off < 64; off <<= 1) {
        s  += __shfl_xor(s, off);
        s2 += __shfl_xor(s2, off);
    }
    __shared__ float red[2][3];
    const int wv = threadIdx.x >> 6;
    if ((threadIdx.x & 63) == 0) { red[0][wv] = s; red[1][wv] = s2; }
    __syncthreads();
    s  = red[0][0] + red[0][1] + red[0][2];
    s2 = red[1][0] + red[1][1] + red[1][2];
    const float mu   = s * (1.f / CC);
    const float var  = s2 * (1.f / CC) - mu * mu;
    const float rstd = rsqrtf(var + 1e-5f);
    const float hval = (hv - mu) * rstd * gamma[c] + beta[c];
    const size_t off = ((row >> 5) * 12 + (c >> 4)) * 512 +
                       ((row & 31) + ((c >> 3) & 1) * 32) * 8 + (c & 7);
    hfrag[off] = f2bf(hval);
}

// ---------------------------------------------------------------------------
extern "C" void kernel_launch(void* const* d_in, const int* in_sizes, int n_in,
                              void* d_out, int out_size, void* d_ws, size_t ws_size,
                              hipStream_t stream)
{
    const float* x    = (const float*)d_in[0];
    const float* Wk   = (const float*)d_in[1];
    const float* Wv   = (const float*)d_in[2];
    const float* Wr   = (const float*)d_in[3];
    const float* Wo   = (const float*)d_in[4];
    const float* ln_g = (const float*)d_in[5];
    const float* ln_b = (const float*)d_in[6];
    const float* wdec = (const float*)d_in[7];
    const float* u    = (const float*)d_in[8];

    unsigned short* kbf   = (unsigned short*)d_ws;
    unsigned short* vbf   = kbf + NNELE;
    unsigned short* rbf   = vbf + NNELE;
    unsigned short* xfrag = rbf + NNELE;
    unsigned short* wfrag = xfrag + NNELE;       // 4*WCH bf16
    float* sp = (float*)xfrag;                   // alias: states after proj
    float* sq = sp + NSTATE;
    float* so = sq + NSTATE;
    unsigned short* hfrag = kbf;                 // alias: h after scans
    unsigned short* yfwd  = (unsigned short*)d_out;  // bf16 staging in d_out
    unsigned short* ybwd  = yfwd + NNELE;
    float* out = (float*)d_out;

    wcvt_frag<<<72, 256, 0, stream>>>(Wk, Wv, Wr, Wo, wfrag);
    xcvt_frag<<<dim3(TPIX / 32, BB), 256, 0, stream>>>(x, xfrag);

    proj_mfma32<<<dim3((BB * TPIX) / 128, 1, 3), 256, 0, stream>>>(
        xfrag, wfrag, kbf, vbf, rbf);

    const int nth = (int)NSTATE;
    wkv_chunk_kernel<<<nth / 256, 256, 0, stream>>>(kbf, vbf, wdec, sp, sq, so);
    wkv_prefix_kernel<<<(2 * BB * CC + 255) / 256, 256, 0, stream>>>(sp, sq, so, wdec);
    wkv_emit_kernel<<<nth / 256, 256, 0, stream>>>(kbf, vbf, wdec, u, sp, sq, so, yfwd, ybwd);

    ln_kernel<<<BB * TPIX, 192, 0, stream>>>(rbf, yfwd, ybwd, ln_g, ln_b, hfrag);

    outproj_mfma32<<<(BB * TPIX) / 128, 256, 0, stream>>>(hfrag, wfrag + 3 * WCH, out);
}